// Round 1
// baseline (386.244 us; speedup 1.0000x reference)
//
#include <hip/hip_runtime.h>

#define N_NODES 50000
#define N_EDGES 800000

static constexpr float SCALE = 0.17677669529663687f; // 1/sqrt(32)

// ---------------- CSR construction ----------------

__global__ void k_zero(int* __restrict__ p, int n) {
    int i = blockIdx.x * 256 + threadIdx.x;
    if (i < n) p[i] = 0;
}

__global__ void k_hist(const int* __restrict__ dst, int* __restrict__ cnt,
                       int* __restrict__ rank, int E) {
    int e = blockIdx.x * 256 + threadIdx.x;
    if (e < E) rank[e] = atomicAdd(&cnt[dst[e]], 1);
}

// exclusive scan over cnt[0..n) -> row[0..n), block partials in bsum
__global__ __launch_bounds__(256) void k_scan1(const int* __restrict__ cnt,
                                               int* __restrict__ row,
                                               int* __restrict__ bsum, int n) {
    __shared__ int wsum[4];
    int t = threadIdx.x;
    int base = blockIdx.x * 1024 + t * 4;
    int v0 = (base + 0 < n) ? cnt[base + 0] : 0;
    int v1 = (base + 1 < n) ? cnt[base + 1] : 0;
    int v2 = (base + 2 < n) ? cnt[base + 2] : 0;
    int v3 = (base + 3 < n) ? cnt[base + 3] : 0;
    int s = v0 + v1 + v2 + v3;
    int lane = t & 63, wid = t >> 6;
    int sc = s;
#pragma unroll
    for (int d = 1; d < 64; d <<= 1) {
        int o = __shfl_up(sc, d);
        if (lane >= d) sc += o;
    }
    if (lane == 63) wsum[wid] = sc;
    __syncthreads();
    int woff = 0;
    for (int w = 0; w < wid; ++w) woff += wsum[w];
    int excl = woff + sc - s;
    if (base + 0 < n) row[base + 0] = excl;
    if (base + 1 < n) row[base + 1] = excl + v0;
    if (base + 2 < n) row[base + 2] = excl + v0 + v1;
    if (base + 3 < n) row[base + 3] = excl + v0 + v1 + v2;
    if (t == 255) bsum[blockIdx.x] = woff + sc;
}

__global__ void k_scan2(const int* __restrict__ bsum, int* __restrict__ boff, int nb) {
    int t = threadIdx.x; // 64 threads, single wave
    int v = (t < nb) ? bsum[t] : 0;
    int sc = v;
#pragma unroll
    for (int d = 1; d < 64; d <<= 1) {
        int o = __shfl_up(sc, d);
        if (t >= d) sc += o;
    }
    boff[t] = sc - v; // exclusive
}

__global__ void k_scan3(int* __restrict__ row, const int* __restrict__ boff,
                        int n, int total) {
    int t = threadIdx.x;
    int base = blockIdx.x * 1024 + t * 4;
    int o = boff[blockIdx.x];
#pragma unroll
    for (int r = 0; r < 4; ++r)
        if (base + r < n) row[base + r] += o;
    if (blockIdx.x == 0 && t == 0) row[n] = total;
}

__global__ void k_scatter(const int* __restrict__ src, const int* __restrict__ dst,
                          const int* __restrict__ row, const int* __restrict__ rank,
                          int* __restrict__ col, int E) {
    int e = blockIdx.x * 256 + threadIdx.x;
    if (e < E) col[row[dst[e]] + rank[e]] = src[e];
}

// ---------------- GEMM 1: x[N,64] @ {Wq,Wk,Wv,Ws}[64,128] + b -> qkvs1[N,512] ----------------

__global__ __launch_bounds__(256) void k_gemm1(
    const float* __restrict__ x,
    const float* __restrict__ W0, const float* __restrict__ b0,
    const float* __restrict__ W1, const float* __restrict__ b1,
    const float* __restrict__ W2, const float* __restrict__ b2,
    const float* __restrict__ W3, const float* __restrict__ b3,
    float* __restrict__ out, int n)
{
    __shared__ float Xs[64][68];   // transposed: Xs[k][r], pad 68 keeps float4 alignment
    __shared__ float Wsh[64][64];
    int t = threadIdx.x;
    int nb = blockIdx.x * 64;
    for (int idx = t; idx < 4096; idx += 256) {
        int r = idx >> 6, k = idx & 63;
        Xs[k][r] = (nb + r < n) ? x[(size_t)(nb + r) * 64 + k] : 0.f;
    }
    const float* Wm[4] = {W0, W1, W2, W3};
    const float* bm[4] = {b0, b1, b2, b3};
    int tx = t & 15, ty = t >> 4;
    for (int cc = 0; cc < 8; ++cc) { // 8 chunks of 64 output cols
        const float* W = Wm[cc >> 1];
        int half = (cc & 1) * 64;
        __syncthreads();
        for (int idx = t; idx < 4096; idx += 256) {
            int k = idx >> 6, c2 = idx & 63;
            Wsh[k][c2] = W[(size_t)k * 128 + half + c2];
        }
        __syncthreads();
        float acc[4][4] = {};
        for (int k = 0; k < 64; ++k) {
            float4 a = *(const float4*)&Xs[k][ty * 4];
            float4 b = *(const float4*)&Wsh[k][tx * 4];
            acc[0][0] += a.x * b.x; acc[0][1] += a.x * b.y; acc[0][2] += a.x * b.z; acc[0][3] += a.x * b.w;
            acc[1][0] += a.y * b.x; acc[1][1] += a.y * b.y; acc[1][2] += a.y * b.z; acc[1][3] += a.y * b.w;
            acc[2][0] += a.z * b.x; acc[2][1] += a.z * b.y; acc[2][2] += a.z * b.z; acc[2][3] += a.z * b.w;
            acc[3][0] += a.w * b.x; acc[3][1] += a.w * b.y; acc[3][2] += a.w * b.z; acc[3][3] += a.w * b.w;
        }
        const float* bb = bm[cc >> 1];
        float4 bias;
        bias.x = bb[half + tx * 4 + 0];
        bias.y = bb[half + tx * 4 + 1];
        bias.z = bb[half + tx * 4 + 2];
        bias.w = bb[half + tx * 4 + 3];
#pragma unroll
        for (int i2 = 0; i2 < 4; ++i2) {
            int rowi = nb + ty * 4 + i2;
            if (rowi < n) {
                float4 o4;
                o4.x = acc[i2][0] + bias.x;
                o4.y = acc[i2][1] + bias.y;
                o4.z = acc[i2][2] + bias.z;
                o4.w = acc[i2][3] + bias.w;
                *(float4*)&out[(size_t)rowi * 512 + cc * 64 + tx * 4] = o4;
            }
        }
    }
}

// ---------------- GEMM 2: h1[N,128] @ {Wq,Wk,Wv,Ws}[128,32] + b -> qkvs2[N,128] ----------------

__global__ __launch_bounds__(256) void k_gemm2(
    const float* __restrict__ h1,
    const float* __restrict__ W0, const float* __restrict__ b0,
    const float* __restrict__ W1, const float* __restrict__ b1,
    const float* __restrict__ W2, const float* __restrict__ b2,
    const float* __restrict__ W3, const float* __restrict__ b3,
    float* __restrict__ out, int n)
{
    __shared__ float Xs[128][68];  // 34.8 KB
    __shared__ float Wsh[128][64]; // 32 KB
    int t = threadIdx.x;
    int nb = blockIdx.x * 64;
    for (int idx = t; idx < 8192; idx += 256) {
        int r = idx >> 7, k = idx & 127;
        Xs[k][r] = (nb + r < n) ? h1[(size_t)(nb + r) * 128 + k] : 0.f;
    }
    const float* Wm[4] = {W0, W1, W2, W3};
    const float* bm[4] = {b0, b1, b2, b3};
    int tx = t & 15, ty = t >> 4;
    for (int hh = 0; hh < 2; ++hh) { // two chunks of 64 cols ({q,k} then {v,s})
        __syncthreads();
        for (int idx = t; idx < 8192; idx += 256) {
            int k = idx >> 6, c2 = idx & 63;
            const float* W = Wm[hh * 2 + (c2 >> 5)];
            Wsh[k][c2] = W[(size_t)k * 32 + (c2 & 31)];
        }
        __syncthreads();
        float acc[4][4] = {};
        for (int k = 0; k < 128; ++k) {
            float4 a = *(const float4*)&Xs[k][ty * 4];
            float4 b = *(const float4*)&Wsh[k][tx * 4];
            acc[0][0] += a.x * b.x; acc[0][1] += a.x * b.y; acc[0][2] += a.x * b.z; acc[0][3] += a.x * b.w;
            acc[1][0] += a.y * b.x; acc[1][1] += a.y * b.y; acc[1][2] += a.y * b.z; acc[1][3] += a.y * b.w;
            acc[2][0] += a.z * b.x; acc[2][1] += a.z * b.y; acc[2][2] += a.z * b.z; acc[2][3] += a.z * b.w;
            acc[3][0] += a.w * b.x; acc[3][1] += a.w * b.y; acc[3][2] += a.w * b.z; acc[3][3] += a.w * b.w;
        }
        int cbase = tx * 4;
        const float* bb = bm[hh * 2 + (cbase >> 5)];
        int cw = cbase & 31;
        float4 bias;
        bias.x = bb[cw + 0]; bias.y = bb[cw + 1]; bias.z = bb[cw + 2]; bias.w = bb[cw + 3];
#pragma unroll
        for (int i2 = 0; i2 < 4; ++i2) {
            int rowi = nb + ty * 4 + i2;
            if (rowi < n) {
                float4 o4;
                o4.x = acc[i2][0] + bias.x;
                o4.y = acc[i2][1] + bias.y;
                o4.z = acc[i2][2] + bias.z;
                o4.w = acc[i2][3] + bias.w;
                *(float4*)&out[(size_t)rowi * 128 + hh * 64 + cbase] = o4;
            }
        }
    }
}

// ---------------- Layer-1 attention aggregate: one wave per dst node ----------------
// qkvs1 row layout: q[0:128] k[128:256] v[256:384] s[384:512]; element = h*32+c
// lane holds elements {lane, lane+64}: heads {lane>>5, (lane>>5)+2}

__global__ __launch_bounds__(256) void k_agg1(
    const float* __restrict__ qkvs, const int* __restrict__ row_ptr,
    const int* __restrict__ col, float* __restrict__ h1, int n)
{
    int i = blockIdx.x * 4 + (threadIdx.x >> 6);
    if (i >= n) return;
    int lane = threadIdx.x & 63;
    const float* bi = qkvs + (size_t)i * 512;
    float q0 = bi[lane], q1 = bi[64 + lane];
    float acc0 = 0.f, acc1 = 0.f, d0 = 0.f, d1 = 0.f;
    int s = row_ptr[i], e = row_ptr[i + 1];
    for (int t = s; t < e; ++t) {
        int j = col[t];
        const float* bj = qkvs + (size_t)j * 512;
        float k0 = bj[128 + lane], k1 = bj[192 + lane];
        float v0 = bj[256 + lane], v1 = bj[320 + lane];
        float t0 = q0 * k0, t1 = q1 * k1;
        t0 += __shfl_xor(t0, 1);  t1 += __shfl_xor(t1, 1);
        t0 += __shfl_xor(t0, 2);  t1 += __shfl_xor(t1, 2);
        t0 += __shfl_xor(t0, 4);  t1 += __shfl_xor(t1, 4);
        t0 += __shfl_xor(t0, 8);  t1 += __shfl_xor(t1, 8);
        t0 += __shfl_xor(t0, 16); t1 += __shfl_xor(t1, 16);
        float p0 = __expf(t0 * SCALE), p1 = __expf(t1 * SCALE);
        d0 += p0; d1 += p1;
        acc0 += p0 * v0; acc1 += p1 * v1;
    }
    float r0 = (d0 > 0.f) ? acc0 / d0 : 0.f;
    float r1 = (d1 > 0.f) ? acc1 / d1 : 0.f;
    r0 += bi[384 + lane];
    r1 += bi[448 + lane];
    r0 = (r0 > 0.f) ? r0 : expm1f(r0); // ELU
    r1 = (r1 > 0.f) ? r1 : expm1f(r1);
    h1[(size_t)i * 128 + lane] = r0;
    h1[(size_t)i * 128 + 64 + lane] = r1;
}

// ---------------- Layer-2 attention aggregate: one wave per dst node, 2 edges/iter ----------------
// qkvs2 row layout: q[0:32] k[32:64] v[64:96] s[96:128]

__global__ __launch_bounds__(256) void k_agg2(
    const float* __restrict__ qkvs2, const int* __restrict__ row_ptr,
    const int* __restrict__ col, float* __restrict__ out, int n)
{
    int i = blockIdx.x * 4 + (threadIdx.x >> 6);
    if (i >= n) return;
    int lane = threadIdx.x & 63;
    int c = lane & 31, sub = lane >> 5;
    const float* bi = qkvs2 + (size_t)i * 128;
    float q = bi[c];
    float acc = 0.f, d = 0.f;
    int s = row_ptr[i], e = row_ptr[i + 1];
    for (int t = s; t < e; t += 2) {
        int te = t + sub;
        bool valid = te < e;
        int j = col[valid ? te : t];
        const float* bj = qkvs2 + (size_t)j * 128;
        float kk = bj[32 + c], vv = bj[64 + c];
        float lg = q * kk;
        lg += __shfl_xor(lg, 1);
        lg += __shfl_xor(lg, 2);
        lg += __shfl_xor(lg, 4);
        lg += __shfl_xor(lg, 8);
        lg += __shfl_xor(lg, 16);
        float p = valid ? __expf(lg * SCALE) : 0.f;
        d += p;
        acc += p * vv;
    }
    acc += __shfl_xor(acc, 32);
    d += __shfl_xor(d, 32);
    if (sub == 0)
        out[(size_t)i * 32 + c] = ((d > 0.f) ? acc / d : 0.f) + bi[96 + c];
}

// ---------------- launch ----------------

extern "C" void kernel_launch(void* const* d_in, const int* in_sizes, int n_in,
                              void* d_out, int out_size, void* d_ws, size_t ws_size,
                              hipStream_t stream)
{
    const int N = N_NODES, E = N_EDGES;
    const float* x   = (const float*)d_in[0];
    const int* edge  = (const int*)d_in[1];
    const int* src   = edge;       // edge_index[0]
    const int* dst   = edge + E;   // edge_index[1]
    const float* Wq1 = (const float*)d_in[2];  const float* bq1 = (const float*)d_in[3];
    const float* Wk1 = (const float*)d_in[4];  const float* bk1 = (const float*)d_in[5];
    const float* Wv1 = (const float*)d_in[6];  const float* bv1 = (const float*)d_in[7];
    const float* Ws1 = (const float*)d_in[8];  const float* bs1 = (const float*)d_in[9];
    const float* Wq2 = (const float*)d_in[10]; const float* bq2 = (const float*)d_in[11];
    const float* Wk2 = (const float*)d_in[12]; const float* bk2 = (const float*)d_in[13];
    const float* Wv2 = (const float*)d_in[14]; const float* bv2 = (const float*)d_in[15];
    const float* Ws2 = (const float*)d_in[16]; const float* bs2 = (const float*)d_in[17];

    char* ws = (char*)d_ws;
    size_t off = 0;
    auto alloc = [&](size_t bytes) -> void* {
        void* p = ws + off;
        off += (bytes + 255) & ~(size_t)255;
        return p;
    };
    float* qkvs1  = (float*)alloc((size_t)N * 512 * 4); // 102.4 MB
    float* h1     = (float*)alloc((size_t)N * 128 * 4); //  25.6 MB
    float* qkvs2  = (float*)alloc((size_t)N * 128 * 4); //  25.6 MB
    int* row_ptr  = (int*)alloc((size_t)(N + 1) * 4);
    int* cnt      = (int*)alloc((size_t)N * 4);
    int* rank     = (int*)alloc((size_t)E * 4);
    int* colb     = (int*)alloc((size_t)E * 4);
    int* bsum     = (int*)alloc(64 * 4);
    int* boff     = (int*)alloc(64 * 4);

    int NBS = (N + 1023) / 1024; // 49 scan blocks

    k_zero<<<(N + 255) / 256, 256, 0, stream>>>(cnt, N);
    k_hist<<<(E + 255) / 256, 256, 0, stream>>>(dst, cnt, rank, E);
    k_scan1<<<NBS, 256, 0, stream>>>(cnt, row_ptr, bsum, N);
    k_scan2<<<1, 64, 0, stream>>>(bsum, boff, NBS);
    k_scan3<<<NBS, 256, 0, stream>>>(row_ptr, boff, N, E);
    k_scatter<<<(E + 255) / 256, 256, 0, stream>>>(src, dst, row_ptr, rank, colb, E);

    k_gemm1<<<(N + 63) / 64, 256, 0, stream>>>(x, Wq1, bq1, Wk1, bk1, Wv1, bv1, Ws1, bs1, qkvs1, N);
    k_agg1<<<(N + 3) / 4, 256, 0, stream>>>(qkvs1, row_ptr, colb, h1, N);
    k_gemm2<<<(N + 63) / 64, 256, 0, stream>>>(h1, Wq2, bq2, Wk2, bk2, Wv2, bv2, Ws2, bs2, qkvs2, N);
    k_agg2<<<(N + 3) / 4, 256, 0, stream>>>(qkvs2, row_ptr, colb, (float*)d_out, N);
}

// Round 2
// 338.293 us; speedup vs baseline: 1.1417x; 1.1417x over previous
//
#include <hip/hip_runtime.h>
#include <hip/hip_bf16.h>

#define N_NODES 50000
#define N_EDGES 800000

static constexpr float SCALE = 0.17677669529663687f; // 1/sqrt(32)

static __device__ inline unsigned short f2bf(float f) {
    __hip_bfloat16 h = __float2bfloat16(f);
    return __builtin_bit_cast(unsigned short, h);
}
static __device__ inline float bf2f(unsigned short u) {
    return __uint_as_float(((unsigned)u) << 16);
}

// ---------------- CSR construction ----------------

__global__ void k_zero(int* __restrict__ p, int n) {
    int i = blockIdx.x * 256 + threadIdx.x;
    if (i < n) p[i] = 0;
}

__global__ void k_hist(const int* __restrict__ dst, int* __restrict__ cnt,
                       int* __restrict__ rank, int E) {
    int e = blockIdx.x * 256 + threadIdx.x;
    if (e < E) rank[e] = atomicAdd(&cnt[dst[e]], 1);
}

// exclusive scan over cnt[0..n) -> row[0..n), block partials in bsum
__global__ __launch_bounds__(256) void k_scan1(const int* __restrict__ cnt,
                                               int* __restrict__ row,
                                               int* __restrict__ bsum, int n) {
    __shared__ int wsum[4];
    int t = threadIdx.x;
    int base = blockIdx.x * 1024 + t * 4;
    int v0 = (base + 0 < n) ? cnt[base + 0] : 0;
    int v1 = (base + 1 < n) ? cnt[base + 1] : 0;
    int v2 = (base + 2 < n) ? cnt[base + 2] : 0;
    int v3 = (base + 3 < n) ? cnt[base + 3] : 0;
    int s = v0 + v1 + v2 + v3;
    int lane = t & 63, wid = t >> 6;
    int sc = s;
#pragma unroll
    for (int d = 1; d < 64; d <<= 1) {
        int o = __shfl_up(sc, d);
        if (lane >= d) sc += o;
    }
    if (lane == 63) wsum[wid] = sc;
    __syncthreads();
    int woff = 0;
    for (int w = 0; w < wid; ++w) woff += wsum[w];
    int excl = woff + sc - s;
    if (base + 0 < n) row[base + 0] = excl;
    if (base + 1 < n) row[base + 1] = excl + v0;
    if (base + 2 < n) row[base + 2] = excl + v0 + v1;
    if (base + 3 < n) row[base + 3] = excl + v0 + v1 + v2;
    if (t == 255) bsum[blockIdx.x] = woff + sc;
}

__global__ void k_scan2(const int* __restrict__ bsum, int* __restrict__ boff, int nb) {
    int t = threadIdx.x; // 64 threads, single wave
    int v = (t < nb) ? bsum[t] : 0;
    int sc = v;
#pragma unroll
    for (int d = 1; d < 64; d <<= 1) {
        int o = __shfl_up(sc, d);
        if (t >= d) sc += o;
    }
    boff[t] = sc - v; // exclusive
}

__global__ void k_scan3(int* __restrict__ row, const int* __restrict__ boff,
                        int n, int total) {
    int t = threadIdx.x;
    int base = blockIdx.x * 1024 + t * 4;
    int o = boff[blockIdx.x];
#pragma unroll
    for (int r = 0; r < 4; ++r)
        if (base + r < n) row[base + r] += o;
    if (blockIdx.x == 0 && t == 0) row[n] = total;
}

__global__ void k_scatter(const int* __restrict__ src, const int* __restrict__ dst,
                          const int* __restrict__ row, const int* __restrict__ rank,
                          int* __restrict__ col, int E) {
    int e = blockIdx.x * 256 + threadIdx.x;
    if (e < E) col[row[dst[e]] + rank[e]] = src[e];
}

// ---------------- GEMM 1: x[N,64] @ {Wq,Wk,Wv,Ws}[64,128] + b ----------------
// outputs: qs1[N][256] fp32 (q 0:128, s 128:256); kv1[N][256] bf16 (k 0:128, v 128:256)

__global__ __launch_bounds__(256) void k_gemm1(
    const float* __restrict__ x,
    const float* __restrict__ W0, const float* __restrict__ b0,
    const float* __restrict__ W1, const float* __restrict__ b1,
    const float* __restrict__ W2, const float* __restrict__ b2,
    const float* __restrict__ W3, const float* __restrict__ b3,
    float* __restrict__ qs1, unsigned short* __restrict__ kv1, int n)
{
    __shared__ float Xs[64][68];   // transposed: Xs[k][r]
    __shared__ float Wsh[64][64];
    int t = threadIdx.x;
    int nb = blockIdx.x * 64;
    for (int idx = t; idx < 4096; idx += 256) {
        int r = idx >> 6, k = idx & 63;
        Xs[k][r] = (nb + r < n) ? x[(size_t)(nb + r) * 64 + k] : 0.f;
    }
    const float* Wm[4] = {W0, W1, W2, W3};
    const float* bm[4] = {b0, b1, b2, b3};
    int tx = t & 15, ty = t >> 4;
    for (int cc = 0; cc < 8; ++cc) { // chunks: 0,1=q 2,3=k 4,5=v 6,7=s
        const float* W = Wm[cc >> 1];
        int half = (cc & 1) * 64;
        __syncthreads();
        for (int idx = t; idx < 4096; idx += 256) {
            int k = idx >> 6, c2 = idx & 63;
            Wsh[k][c2] = W[(size_t)k * 128 + half + c2];
        }
        __syncthreads();
        float acc[4][4] = {};
        for (int k = 0; k < 64; ++k) {
            float4 a = *(const float4*)&Xs[k][ty * 4];
            float4 b = *(const float4*)&Wsh[k][tx * 4];
            acc[0][0] += a.x * b.x; acc[0][1] += a.x * b.y; acc[0][2] += a.x * b.z; acc[0][3] += a.x * b.w;
            acc[1][0] += a.y * b.x; acc[1][1] += a.y * b.y; acc[1][2] += a.y * b.z; acc[1][3] += a.y * b.w;
            acc[2][0] += a.z * b.x; acc[2][1] += a.z * b.y; acc[2][2] += a.z * b.z; acc[2][3] += a.z * b.w;
            acc[3][0] += a.w * b.x; acc[3][1] += a.w * b.y; acc[3][2] += a.w * b.z; acc[3][3] += a.w * b.w;
        }
        const float* bb = bm[cc >> 1];
        float4 bias;
        bias.x = bb[half + tx * 4 + 0];
        bias.y = bb[half + tx * 4 + 1];
        bias.z = bb[half + tx * 4 + 2];
        bias.w = bb[half + tx * 4 + 3];
#pragma unroll
        for (int i2 = 0; i2 < 4; ++i2) {
            int rowi = nb + ty * 4 + i2;
            if (rowi < n) {
                float4 o4;
                o4.x = acc[i2][0] + bias.x;
                o4.y = acc[i2][1] + bias.y;
                o4.z = acc[i2][2] + bias.z;
                o4.w = acc[i2][3] + bias.w;
                if (cc < 2 || cc >= 6) {
                    int base = (cc < 2) ? cc * 64 : 128 + (cc - 6) * 64;
                    *(float4*)&qs1[(size_t)rowi * 256 + base + tx * 4] = o4;
                } else {
                    int base = (cc < 4) ? (cc - 2) * 64 : 128 + (cc - 4) * 64;
                    ushort4 u;
                    u.x = f2bf(o4.x); u.y = f2bf(o4.y); u.z = f2bf(o4.z); u.w = f2bf(o4.w);
                    *(ushort4*)&kv1[(size_t)rowi * 256 + base + tx * 4] = u;
                }
            }
        }
    }
}

// ---------------- GEMM 2: h1[N,128] @ {Wq,Wk,Wv,Ws}[128,32] + b ----------------
// outputs: qs2[N][64] fp32 (q 0:32, s 32:64); kv2[N][64] bf16 (k 0:32, v 32:64)

__global__ __launch_bounds__(256) void k_gemm2(
    const float* __restrict__ h1,
    const float* __restrict__ W0, const float* __restrict__ b0,
    const float* __restrict__ W1, const float* __restrict__ b1,
    const float* __restrict__ W2, const float* __restrict__ b2,
    const float* __restrict__ W3, const float* __restrict__ b3,
    float* __restrict__ qs2, unsigned short* __restrict__ kv2, int n)
{
    __shared__ float Xs[128][68];
    __shared__ float Wsh[128][64];
    int t = threadIdx.x;
    int nb = blockIdx.x * 64;
    for (int idx = t; idx < 8192; idx += 256) {
        int r = idx >> 7, k = idx & 127;
        Xs[k][r] = (nb + r < n) ? h1[(size_t)(nb + r) * 128 + k] : 0.f;
    }
    const float* Wm[4] = {W0, W1, W2, W3};
    const float* bm[4] = {b0, b1, b2, b3};
    int tx = t & 15, ty = t >> 4;
    for (int hh = 0; hh < 2; ++hh) { // hh=0: {q,k}, hh=1: {v,s}
        __syncthreads();
        for (int idx = t; idx < 8192; idx += 256) {
            int k = idx >> 6, c2 = idx & 63;
            const float* W = Wm[hh * 2 + (c2 >> 5)];
            Wsh[k][c2] = W[(size_t)k * 32 + (c2 & 31)];
        }
        __syncthreads();
        float acc[4][4] = {};
        for (int k = 0; k < 128; ++k) {
            float4 a = *(const float4*)&Xs[k][ty * 4];
            float4 b = *(const float4*)&Wsh[k][tx * 4];
            acc[0][0] += a.x * b.x; acc[0][1] += a.x * b.y; acc[0][2] += a.x * b.z; acc[0][3] += a.x * b.w;
            acc[1][0] += a.y * b.x; acc[1][1] += a.y * b.y; acc[1][2] += a.y * b.z; acc[1][3] += a.y * b.w;
            acc[2][0] += a.z * b.x; acc[2][1] += a.z * b.y; acc[2][2] += a.z * b.z; acc[2][3] += a.z * b.w;
            acc[3][0] += a.w * b.x; acc[3][1] += a.w * b.y; acc[3][2] += a.w * b.z; acc[3][3] += a.w * b.w;
        }
        int cbase = tx * 4;
        const float* bb = bm[hh * 2 + (cbase >> 5)];
        int cw = cbase & 31;
        float4 bias;
        bias.x = bb[cw + 0]; bias.y = bb[cw + 1]; bias.z = bb[cw + 2]; bias.w = bb[cw + 3];
#pragma unroll
        for (int i2 = 0; i2 < 4; ++i2) {
            int rowi = nb + ty * 4 + i2;
            if (rowi < n) {
                float4 o4;
                o4.x = acc[i2][0] + bias.x;
                o4.y = acc[i2][1] + bias.y;
                o4.z = acc[i2][2] + bias.z;
                o4.w = acc[i2][3] + bias.w;
                if (hh == 0) {
                    if (cbase < 32) { // q -> fp32
                        *(float4*)&qs2[(size_t)rowi * 64 + cbase] = o4;
                    } else {          // k -> bf16
                        ushort4 u;
                        u.x = f2bf(o4.x); u.y = f2bf(o4.y); u.z = f2bf(o4.z); u.w = f2bf(o4.w);
                        *(ushort4*)&kv2[(size_t)rowi * 64 + (cbase - 32)] = u;
                    }
                } else {
                    if (cbase < 32) { // v -> bf16
                        ushort4 u;
                        u.x = f2bf(o4.x); u.y = f2bf(o4.y); u.z = f2bf(o4.z); u.w = f2bf(o4.w);
                        *(ushort4*)&kv2[(size_t)rowi * 64 + 32 + cbase] = u;
                    } else {          // s -> fp32
                        *(float4*)&qs2[(size_t)rowi * 64 + cbase] = o4;
                    }
                }
            }
        }
    }
}

// ---------------- Layer-1 attention aggregate ----------------
// one wave per dst node; lane l owns elements {2l, 2l+1} of the 128-dim (h,c) flat;
// head h = l>>4 -> per-head dot reduces over 16-lane groups.

__global__ __launch_bounds__(256) void k_agg1(
    const float* __restrict__ qs1, const unsigned short* __restrict__ kv1,
    const int* __restrict__ row_ptr, const int* __restrict__ col,
    float* __restrict__ h1, int n)
{
    int i = blockIdx.x * 4 + (threadIdx.x >> 6);
    if (i >= n) return;
    int lane = threadIdx.x & 63;
    const float2 q = *(const float2*)&qs1[(size_t)i * 256 + 2 * lane];
    float ax = 0.f, ay = 0.f, d = 0.f;
    int s = row_ptr[i], e = row_ptr[i + 1];
    for (int t = s; t < e; ++t) {
        int j = col[t];
        const unsigned short* kvj = kv1 + (size_t)j * 256;
        ushort2 ku = *(const ushort2*)&kvj[2 * lane];
        ushort2 vu = *(const ushort2*)&kvj[128 + 2 * lane];
        float lg = q.x * bf2f(ku.x) + q.y * bf2f(ku.y);
        lg += __shfl_xor(lg, 1);
        lg += __shfl_xor(lg, 2);
        lg += __shfl_xor(lg, 4);
        lg += __shfl_xor(lg, 8);
        float p = __expf(lg * SCALE);
        d += p;
        ax += p * bf2f(vu.x);
        ay += p * bf2f(vu.y);
    }
    float rx = (d > 0.f) ? ax / d : 0.f;
    float ry = (d > 0.f) ? ay / d : 0.f;
    const float2 sv = *(const float2*)&qs1[(size_t)i * 256 + 128 + 2 * lane];
    rx += sv.x; ry += sv.y;
    rx = (rx > 0.f) ? rx : expm1f(rx); // ELU
    ry = (ry > 0.f) ? ry : expm1f(ry);
    *(float2*)&h1[(size_t)i * 128 + 2 * lane] = make_float2(rx, ry);
}

// ---------------- Layer-2 attention aggregate ----------------
// one wave per dst node, 4 edges/iter; 16-lane group g handles edge t+g,
// lane c=lane&15 owns channels {2c, 2c+1} of 32.

__global__ __launch_bounds__(256) void k_agg2(
    const float* __restrict__ qs2, const unsigned short* __restrict__ kv2,
    const int* __restrict__ row_ptr, const int* __restrict__ col,
    float* __restrict__ out, int n)
{
    int i = blockIdx.x * 4 + (threadIdx.x >> 6);
    if (i >= n) return;
    int lane = threadIdx.x & 63;
    int g = lane >> 4, c = lane & 15;
    const float2 q = *(const float2*)&qs2[(size_t)i * 64 + 2 * c];
    float ax = 0.f, ay = 0.f, d = 0.f;
    int s = row_ptr[i], e = row_ptr[i + 1];
    for (int t = s; t < e; t += 4) {
        int te = t + g;
        bool valid = te < e;
        int j = col[valid ? te : t];
        const unsigned short* kvj = kv2 + (size_t)j * 64;
        ushort2 ku = *(const ushort2*)&kvj[2 * c];
        ushort2 vu = *(const ushort2*)&kvj[32 + 2 * c];
        float lg = q.x * bf2f(ku.x) + q.y * bf2f(ku.y);
        lg += __shfl_xor(lg, 1);
        lg += __shfl_xor(lg, 2);
        lg += __shfl_xor(lg, 4);
        lg += __shfl_xor(lg, 8);
        float p = valid ? __expf(lg * SCALE) : 0.f;
        d += p;
        ax += p * bf2f(vu.x);
        ay += p * bf2f(vu.y);
    }
    ax += __shfl_xor(ax, 16); ay += __shfl_xor(ay, 16); d += __shfl_xor(d, 16);
    ax += __shfl_xor(ax, 32); ay += __shfl_xor(ay, 32); d += __shfl_xor(d, 32);
    if (g == 0) {
        float rx = (d > 0.f) ? ax / d : 0.f;
        float ry = (d > 0.f) ? ay / d : 0.f;
        const float2 sv = *(const float2*)&qs2[(size_t)i * 64 + 32 + 2 * c];
        *(float2*)&out[(size_t)i * 32 + 2 * c] = make_float2(rx + sv.x, ry + sv.y);
    }
}

// ---------------- launch ----------------

extern "C" void kernel_launch(void* const* d_in, const int* in_sizes, int n_in,
                              void* d_out, int out_size, void* d_ws, size_t ws_size,
                              hipStream_t stream)
{
    const int N = N_NODES, E = N_EDGES;
    const float* x   = (const float*)d_in[0];
    const int* edge  = (const int*)d_in[1];
    const int* src   = edge;       // edge_index[0]
    const int* dst   = edge + E;   // edge_index[1]
    const float* Wq1 = (const float*)d_in[2];  const float* bq1 = (const float*)d_in[3];
    const float* Wk1 = (const float*)d_in[4];  const float* bk1 = (const float*)d_in[5];
    const float* Wv1 = (const float*)d_in[6];  const float* bv1 = (const float*)d_in[7];
    const float* Ws1 = (const float*)d_in[8];  const float* bs1 = (const float*)d_in[9];
    const float* Wq2 = (const float*)d_in[10]; const float* bq2 = (const float*)d_in[11];
    const float* Wk2 = (const float*)d_in[12]; const float* bk2 = (const float*)d_in[13];
    const float* Wv2 = (const float*)d_in[14]; const float* bv2 = (const float*)d_in[15];
    const float* Ws2 = (const float*)d_in[16]; const float* bs2 = (const float*)d_in[17];

    char* ws = (char*)d_ws;
    size_t off = 0;
    auto alloc = [&](size_t bytes) -> void* {
        void* p = ws + off;
        off += (bytes + 255) & ~(size_t)255;
        return p;
    };
    float*          qs1 = (float*)alloc((size_t)N * 256 * 4);          // 51.2 MB
    unsigned short* kv1 = (unsigned short*)alloc((size_t)N * 256 * 2); // 25.6 MB
    float*          h1  = (float*)alloc((size_t)N * 128 * 4);          // 25.6 MB
    float*          qs2 = (float*)alloc((size_t)N * 64 * 4);           // 12.8 MB
    unsigned short* kv2 = (unsigned short*)alloc((size_t)N * 64 * 2);  //  6.4 MB
    int* row_ptr  = (int*)alloc((size_t)(N + 1) * 4);
    int* cnt      = (int*)alloc((size_t)N * 4);
    int* rank     = (int*)alloc((size_t)E * 4);
    int* colb     = (int*)alloc((size_t)E * 4);
    int* bsum     = (int*)alloc(64 * 4);
    int* boff     = (int*)alloc(64 * 4);

    int NBS = (N + 1023) / 1024; // 49 scan blocks

    k_zero<<<(N + 255) / 256, 256, 0, stream>>>(cnt, N);
    k_hist<<<(E + 255) / 256, 256, 0, stream>>>(dst, cnt, rank, E);
    k_scan1<<<NBS, 256, 0, stream>>>(cnt, row_ptr, bsum, N);
    k_scan2<<<1, 64, 0, stream>>>(bsum, boff, NBS);
    k_scan3<<<NBS, 256, 0, stream>>>(row_ptr, boff, N, E);
    k_scatter<<<(E + 255) / 256, 256, 0, stream>>>(src, dst, row_ptr, rank, colb, E);

    k_gemm1<<<(N + 63) / 64, 256, 0, stream>>>(x, Wq1, bq1, Wk1, bk1, Wv1, bv1, Ws1, bs1, qs1, kv1, N);
    k_agg1<<<(N + 3) / 4, 256, 0, stream>>>(qs1, kv1, row_ptr, colb, h1, N);
    k_gemm2<<<(N + 63) / 64, 256, 0, stream>>>(h1, Wq2, bq2, Wk2, bk2, Wv2, bv2, Ws2, bs2, qs2, kv2, N);
    k_agg2<<<(N + 3) / 4, 256, 0, stream>>>(qs2, kv2, row_ptr, colb, (float*)d_out, N);
}

// Round 3
// 290.804 us; speedup vs baseline: 1.3282x; 1.1633x over previous
//
#include <hip/hip_runtime.h>
#include <hip/hip_bf16.h>

#define N_NODES 50000
#define N_EDGES 800000

static constexpr float SCALE = 0.17677669529663687f; // 1/sqrt(32)

static __device__ inline unsigned short f2bf(float f) {
    __hip_bfloat16 h = __float2bfloat16(f);
    return __builtin_bit_cast(unsigned short, h);
}
// unpack a packed pair of bf16 (one u32) -> two floats (x=low half, y=high half)
static __device__ inline float2 bfpair(unsigned u) {
    return make_float2(__uint_as_float(u << 16),
                       __uint_as_float(u & 0xffff0000u));
}

// ---------------- CSR construction ----------------

__global__ void k_zero(int* __restrict__ p, int n) {
    int i = blockIdx.x * 256 + threadIdx.x;
    if (i < n) p[i] = 0;
}

__global__ void k_hist(const int* __restrict__ dst, int* __restrict__ cnt,
                       int* __restrict__ rank, int E) {
    int e = blockIdx.x * 256 + threadIdx.x;
    if (e < E) rank[e] = atomicAdd(&cnt[dst[e]], 1);
}

__global__ __launch_bounds__(256) void k_scan1(const int* __restrict__ cnt,
                                               int* __restrict__ row,
                                               int* __restrict__ bsum, int n) {
    __shared__ int wsum[4];
    int t = threadIdx.x;
    int base = blockIdx.x * 1024 + t * 4;
    int v0 = (base + 0 < n) ? cnt[base + 0] : 0;
    int v1 = (base + 1 < n) ? cnt[base + 1] : 0;
    int v2 = (base + 2 < n) ? cnt[base + 2] : 0;
    int v3 = (base + 3 < n) ? cnt[base + 3] : 0;
    int s = v0 + v1 + v2 + v3;
    int lane = t & 63, wid = t >> 6;
    int sc = s;
#pragma unroll
    for (int d = 1; d < 64; d <<= 1) {
        int o = __shfl_up(sc, d);
        if (lane >= d) sc += o;
    }
    if (lane == 63) wsum[wid] = sc;
    __syncthreads();
    int woff = 0;
    for (int w = 0; w < wid; ++w) woff += wsum[w];
    int excl = woff + sc - s;
    if (base + 0 < n) row[base + 0] = excl;
    if (base + 1 < n) row[base + 1] = excl + v0;
    if (base + 2 < n) row[base + 2] = excl + v0 + v1;
    if (base + 3 < n) row[base + 3] = excl + v0 + v1 + v2;
    if (t == 255) bsum[blockIdx.x] = woff + sc;
}

__global__ void k_scan2(const int* __restrict__ bsum, int* __restrict__ boff, int nb) {
    int t = threadIdx.x; // 64 threads, single wave
    int v = (t < nb) ? bsum[t] : 0;
    int sc = v;
#pragma unroll
    for (int d = 1; d < 64; d <<= 1) {
        int o = __shfl_up(sc, d);
        if (t >= d) sc += o;
    }
    boff[t] = sc - v; // exclusive
}

__global__ void k_scan3(int* __restrict__ row, const int* __restrict__ boff,
                        int n, int total) {
    int t = threadIdx.x;
    int base = blockIdx.x * 1024 + t * 4;
    int o = boff[blockIdx.x];
#pragma unroll
    for (int r = 0; r < 4; ++r)
        if (base + r < n) row[base + r] += o;
    if (blockIdx.x == 0 && t == 0) row[n] = total;
}

__global__ void k_scatter(const int* __restrict__ src, const int* __restrict__ dst,
                          const int* __restrict__ row, const int* __restrict__ rank,
                          int* __restrict__ col, int E) {
    int e = blockIdx.x * 256 + threadIdx.x;
    if (e < E) col[row[dst[e]] + rank[e]] = src[e];
}

// ---------------- GEMM 1: x[N,64] @ {Wq,Wk,Wv,Ws}[64,128] + b ----------------
// outputs: qs1[N][256] fp32 (q 0:128, s 128:256); kv1[N][256] bf16 (k 0:128, v 128:256)

__global__ __launch_bounds__(256) void k_gemm1(
    const float* __restrict__ x,
    const float* __restrict__ W0, const float* __restrict__ b0,
    const float* __restrict__ W1, const float* __restrict__ b1,
    const float* __restrict__ W2, const float* __restrict__ b2,
    const float* __restrict__ W3, const float* __restrict__ b3,
    float* __restrict__ qs1, unsigned short* __restrict__ kv1, int n)
{
    __shared__ float Xs[64][68];
    __shared__ float Wsh[64][64];
    int t = threadIdx.x;
    int nb = blockIdx.x * 64;
    for (int idx = t; idx < 4096; idx += 256) {
        int r = idx >> 6, k = idx & 63;
        Xs[k][r] = (nb + r < n) ? x[(size_t)(nb + r) * 64 + k] : 0.f;
    }
    const float* Wm[4] = {W0, W1, W2, W3};
    const float* bm[4] = {b0, b1, b2, b3};
    int tx = t & 15, ty = t >> 4;
    for (int cc = 0; cc < 8; ++cc) { // chunks: 0,1=q 2,3=k 4,5=v 6,7=s
        const float* W = Wm[cc >> 1];
        int half = (cc & 1) * 64;
        __syncthreads();
        for (int idx = t; idx < 4096; idx += 256) {
            int k = idx >> 6, c2 = idx & 63;
            Wsh[k][c2] = W[(size_t)k * 128 + half + c2];
        }
        __syncthreads();
        float acc[4][4] = {};
        for (int k = 0; k < 64; ++k) {
            float4 a = *(const float4*)&Xs[k][ty * 4];
            float4 b = *(const float4*)&Wsh[k][tx * 4];
            acc[0][0] += a.x * b.x; acc[0][1] += a.x * b.y; acc[0][2] += a.x * b.z; acc[0][3] += a.x * b.w;
            acc[1][0] += a.y * b.x; acc[1][1] += a.y * b.y; acc[1][2] += a.y * b.z; acc[1][3] += a.y * b.w;
            acc[2][0] += a.z * b.x; acc[2][1] += a.z * b.y; acc[2][2] += a.z * b.z; acc[2][3] += a.z * b.w;
            acc[3][0] += a.w * b.x; acc[3][1] += a.w * b.y; acc[3][2] += a.w * b.z; acc[3][3] += a.w * b.w;
        }
        const float* bb = bm[cc >> 1];
        float4 bias;
        bias.x = bb[half + tx * 4 + 0];
        bias.y = bb[half + tx * 4 + 1];
        bias.z = bb[half + tx * 4 + 2];
        bias.w = bb[half + tx * 4 + 3];
#pragma unroll
        for (int i2 = 0; i2 < 4; ++i2) {
            int rowi = nb + ty * 4 + i2;
            if (rowi < n) {
                float4 o4;
                o4.x = acc[i2][0] + bias.x;
                o4.y = acc[i2][1] + bias.y;
                o4.z = acc[i2][2] + bias.z;
                o4.w = acc[i2][3] + bias.w;
                if (cc < 2 || cc >= 6) {
                    int base = (cc < 2) ? cc * 64 : 128 + (cc - 6) * 64;
                    *(float4*)&qs1[(size_t)rowi * 256 + base + tx * 4] = o4;
                } else {
                    int base = (cc < 4) ? (cc - 2) * 64 : 128 + (cc - 4) * 64;
                    ushort4 u;
                    u.x = f2bf(o4.x); u.y = f2bf(o4.y); u.z = f2bf(o4.z); u.w = f2bf(o4.w);
                    *(ushort4*)&kv1[(size_t)rowi * 256 + base + tx * 4] = u;
                }
            }
        }
    }
}

// ---------------- GEMM 2: h1[N,128] @ {Wq,Wk,Wv,Ws}[128,32] + b ----------------
// outputs: qs2[N][64] fp32 (q 0:32, s 32:64); kv2[N][64] bf16 (k 0:32, v 32:64)

__global__ __launch_bounds__(256) void k_gemm2(
    const float* __restrict__ h1,
    const float* __restrict__ W0, const float* __restrict__ b0,
    const float* __restrict__ W1, const float* __restrict__ b1,
    const float* __restrict__ W2, const float* __restrict__ b2,
    const float* __restrict__ W3, const float* __restrict__ b3,
    float* __restrict__ qs2, unsigned short* __restrict__ kv2, int n)
{
    __shared__ float Xs[128][68];
    __shared__ float Wsh[128][64];
    int t = threadIdx.x;
    int nb = blockIdx.x * 64;
    for (int idx = t; idx < 8192; idx += 256) {
        int r = idx >> 7, k = idx & 127;
        Xs[k][r] = (nb + r < n) ? h1[(size_t)(nb + r) * 128 + k] : 0.f;
    }
    const float* Wm[4] = {W0, W1, W2, W3};
    const float* bm[4] = {b0, b1, b2, b3};
    int tx = t & 15, ty = t >> 4;
    for (int hh = 0; hh < 2; ++hh) { // hh=0: {q,k}, hh=1: {v,s}
        __syncthreads();
        for (int idx = t; idx < 8192; idx += 256) {
            int k = idx >> 6, c2 = idx & 63;
            const float* W = Wm[hh * 2 + (c2 >> 5)];
            Wsh[k][c2] = W[(size_t)k * 32 + (c2 & 31)];
        }
        __syncthreads();
        float acc[4][4] = {};
        for (int k = 0; k < 128; ++k) {
            float4 a = *(const float4*)&Xs[k][ty * 4];
            float4 b = *(const float4*)&Wsh[k][tx * 4];
            acc[0][0] += a.x * b.x; acc[0][1] += a.x * b.y; acc[0][2] += a.x * b.z; acc[0][3] += a.x * b.w;
            acc[1][0] += a.y * b.x; acc[1][1] += a.y * b.y; acc[1][2] += a.y * b.z; acc[1][3] += a.y * b.w;
            acc[2][0] += a.z * b.x; acc[2][1] += a.z * b.y; acc[2][2] += a.z * b.z; acc[2][3] += a.z * b.w;
            acc[3][0] += a.w * b.x; acc[3][1] += a.w * b.y; acc[3][2] += a.w * b.z; acc[3][3] += a.w * b.w;
        }
        int cbase = tx * 4;
        const float* bb = bm[hh * 2 + (cbase >> 5)];
        int cw = cbase & 31;
        float4 bias;
        bias.x = bb[cw + 0]; bias.y = bb[cw + 1]; bias.z = bb[cw + 2]; bias.w = bb[cw + 3];
#pragma unroll
        for (int i2 = 0; i2 < 4; ++i2) {
            int rowi = nb + ty * 4 + i2;
            if (rowi < n) {
                float4 o4;
                o4.x = acc[i2][0] + bias.x;
                o4.y = acc[i2][1] + bias.y;
                o4.z = acc[i2][2] + bias.z;
                o4.w = acc[i2][3] + bias.w;
                if (hh == 0) {
                    if (cbase < 32) {
                        *(float4*)&qs2[(size_t)rowi * 64 + cbase] = o4;
                    } else {
                        ushort4 u;
                        u.x = f2bf(o4.x); u.y = f2bf(o4.y); u.z = f2bf(o4.z); u.w = f2bf(o4.w);
                        *(ushort4*)&kv2[(size_t)rowi * 64 + (cbase - 32)] = u;
                    }
                } else {
                    if (cbase < 32) {
                        ushort4 u;
                        u.x = f2bf(o4.x); u.y = f2bf(o4.y); u.z = f2bf(o4.z); u.w = f2bf(o4.w);
                        *(ushort4*)&kv2[(size_t)rowi * 64 + 32 + cbase] = u;
                    } else {
                        *(float4*)&qs2[(size_t)rowi * 64 + cbase] = o4;
                    }
                }
            }
        }
    }
}

// ---------------- Layer-1 attention aggregate ----------------
// one wave per dst node; lane l owns packed elements {2l, 2l+1} (one uint) of the
// 128-dim (h,c) flat; head h = l>>4 -> per-head dot reduces over 16-lane groups.
// Unrolled 4 edges/iteration for memory-level parallelism (latency-bound kernel).

__global__ __launch_bounds__(256) void k_agg1(
    const float* __restrict__ qs1, const unsigned int* __restrict__ kv1,
    const int* __restrict__ row_ptr, const int* __restrict__ col,
    float* __restrict__ h1, int n)
{
    int i = blockIdx.x * 4 + (threadIdx.x >> 6);
    if (i >= n) return;
    int lane = threadIdx.x & 63;
    const float2 q = *(const float2*)&qs1[(size_t)i * 256 + 2 * lane];
    float ax = 0.f, ay = 0.f, d = 0.f;
    int s = row_ptr[i], e = row_ptr[i + 1];
    int t = s;
    for (; t + 4 <= e; t += 4) {
        int j0 = col[t], j1 = col[t + 1], j2 = col[t + 2], j3 = col[t + 3];
        const unsigned* p0 = kv1 + (size_t)j0 * 128;
        const unsigned* p1 = kv1 + (size_t)j1 * 128;
        const unsigned* p2 = kv1 + (size_t)j2 * 128;
        const unsigned* p3 = kv1 + (size_t)j3 * 128;
        unsigned ku0 = p0[lane],      ku1 = p1[lane],      ku2 = p2[lane],      ku3 = p3[lane];
        unsigned vu0 = p0[64 + lane], vu1 = p1[64 + lane], vu2 = p2[64 + lane], vu3 = p3[64 + lane];
        float2 k0 = bfpair(ku0), k1 = bfpair(ku1), k2 = bfpair(ku2), k3 = bfpair(ku3);
        float lg0 = q.x * k0.x + q.y * k0.y;
        float lg1 = q.x * k1.x + q.y * k1.y;
        float lg2 = q.x * k2.x + q.y * k2.y;
        float lg3 = q.x * k3.x + q.y * k3.y;
        lg0 += __shfl_xor(lg0, 1);  lg1 += __shfl_xor(lg1, 1);  lg2 += __shfl_xor(lg2, 1);  lg3 += __shfl_xor(lg3, 1);
        lg0 += __shfl_xor(lg0, 2);  lg1 += __shfl_xor(lg1, 2);  lg2 += __shfl_xor(lg2, 2);  lg3 += __shfl_xor(lg3, 2);
        lg0 += __shfl_xor(lg0, 4);  lg1 += __shfl_xor(lg1, 4);  lg2 += __shfl_xor(lg2, 4);  lg3 += __shfl_xor(lg3, 4);
        lg0 += __shfl_xor(lg0, 8);  lg1 += __shfl_xor(lg1, 8);  lg2 += __shfl_xor(lg2, 8);  lg3 += __shfl_xor(lg3, 8);
        float w0 = __expf(lg0 * SCALE), w1 = __expf(lg1 * SCALE);
        float w2 = __expf(lg2 * SCALE), w3 = __expf(lg3 * SCALE);
        float2 v0 = bfpair(vu0), v1 = bfpair(vu1), v2 = bfpair(vu2), v3 = bfpair(vu3);
        d  += (w0 + w1) + (w2 + w3);
        ax += w0 * v0.x + w1 * v1.x + w2 * v2.x + w3 * v3.x;
        ay += w0 * v0.y + w1 * v1.y + w2 * v2.y + w3 * v3.y;
    }
    for (; t < e; ++t) {
        int j = col[t];
        const unsigned* p = kv1 + (size_t)j * 128;
        unsigned ku = p[lane], vu = p[64 + lane];
        float2 kk = bfpair(ku);
        float lg = q.x * kk.x + q.y * kk.y;
        lg += __shfl_xor(lg, 1);
        lg += __shfl_xor(lg, 2);
        lg += __shfl_xor(lg, 4);
        lg += __shfl_xor(lg, 8);
        float w = __expf(lg * SCALE);
        float2 vv = bfpair(vu);
        d += w; ax += w * vv.x; ay += w * vv.y;
    }
    float rx = (d > 0.f) ? ax / d : 0.f;
    float ry = (d > 0.f) ? ay / d : 0.f;
    const float2 sv = *(const float2*)&qs1[(size_t)i * 256 + 128 + 2 * lane];
    rx += sv.x; ry += sv.y;
    rx = (rx > 0.f) ? rx : expm1f(rx); // ELU
    ry = (ry > 0.f) ? ry : expm1f(ry);
    *(float2*)&h1[(size_t)i * 128 + 2 * lane] = make_float2(rx, ry);
}

// ---------------- Layer-2 attention aggregate ----------------
// one wave per dst node; 16-lane group g handles edges t+g and t+4+g (8 edges/iter);
// lane c=lane&15 owns channels {2c, 2c+1}.

__global__ __launch_bounds__(256) void k_agg2(
    const float* __restrict__ qs2, const unsigned int* __restrict__ kv2,
    const int* __restrict__ row_ptr, const int* __restrict__ col,
    float* __restrict__ out, int n)
{
    int i = blockIdx.x * 4 + (threadIdx.x >> 6);
    if (i >= n) return;
    int lane = threadIdx.x & 63;
    int g = lane >> 4, c = lane & 15;
    const float2 q = *(const float2*)&qs2[(size_t)i * 64 + 2 * c];
    float ax = 0.f, ay = 0.f, d = 0.f;
    int s = row_ptr[i], e = row_ptr[i + 1];
    for (int t = s; t < e; t += 8) {
        int t0 = t + g, t1 = t + 4 + g;
        bool va = t0 < e, vb = t1 < e;
        int j0 = col[va ? t0 : s];
        int j1 = col[vb ? t1 : s];
        const unsigned* p0 = kv2 + (size_t)j0 * 32;
        const unsigned* p1 = kv2 + (size_t)j1 * 32;
        unsigned ku0 = p0[c], vu0 = p0[16 + c];
        unsigned ku1 = p1[c], vu1 = p1[16 + c];
        float2 k0 = bfpair(ku0), k1 = bfpair(ku1);
        float lg0 = q.x * k0.x + q.y * k0.y;
        float lg1 = q.x * k1.x + q.y * k1.y;
        lg0 += __shfl_xor(lg0, 1);  lg1 += __shfl_xor(lg1, 1);
        lg0 += __shfl_xor(lg0, 2);  lg1 += __shfl_xor(lg1, 2);
        lg0 += __shfl_xor(lg0, 4);  lg1 += __shfl_xor(lg1, 4);
        lg0 += __shfl_xor(lg0, 8);  lg1 += __shfl_xor(lg1, 8);
        float w0 = va ? __expf(lg0 * SCALE) : 0.f;
        float w1 = vb ? __expf(lg1 * SCALE) : 0.f;
        float2 v0 = bfpair(vu0), v1 = bfpair(vu1);
        d += w0 + w1;
        ax += w0 * v0.x + w1 * v1.x;
        ay += w0 * v0.y + w1 * v1.y;
    }
    ax += __shfl_xor(ax, 16); ay += __shfl_xor(ay, 16); d += __shfl_xor(d, 16);
    ax += __shfl_xor(ax, 32); ay += __shfl_xor(ay, 32); d += __shfl_xor(d, 32);
    if (g == 0) {
        float rx = (d > 0.f) ? ax / d : 0.f;
        float ry = (d > 0.f) ? ay / d : 0.f;
        const float2 sv = *(const float2*)&qs2[(size_t)i * 64 + 32 + 2 * c];
        *(float2*)&out[(size_t)i * 32 + 2 * c] = make_float2(rx + sv.x, ry + sv.y);
    }
}

// ---------------- launch ----------------

extern "C" void kernel_launch(void* const* d_in, const int* in_sizes, int n_in,
                              void* d_out, int out_size, void* d_ws, size_t ws_size,
                              hipStream_t stream)
{
    const int N = N_NODES, E = N_EDGES;
    const float* x   = (const float*)d_in[0];
    const int* edge  = (const int*)d_in[1];
    const int* src   = edge;       // edge_index[0]
    const int* dst   = edge + E;   // edge_index[1]
    const float* Wq1 = (const float*)d_in[2];  const float* bq1 = (const float*)d_in[3];
    const float* Wk1 = (const float*)d_in[4];  const float* bk1 = (const float*)d_in[5];
    const float* Wv1 = (const float*)d_in[6];  const float* bv1 = (const float*)d_in[7];
    const float* Ws1 = (const float*)d_in[8];  const float* bs1 = (const float*)d_in[9];
    const float* Wq2 = (const float*)d_in[10]; const float* bq2 = (const float*)d_in[11];
    const float* Wk2 = (const float*)d_in[12]; const float* bk2 = (const float*)d_in[13];
    const float* Wv2 = (const float*)d_in[14]; const float* bv2 = (const float*)d_in[15];
    const float* Ws2 = (const float*)d_in[16]; const float* bs2 = (const float*)d_in[17];

    char* ws = (char*)d_ws;
    size_t off = 0;
    auto alloc = [&](size_t bytes) -> void* {
        void* p = ws + off;
        off += (bytes + 255) & ~(size_t)255;
        return p;
    };
    float*          qs1 = (float*)alloc((size_t)N * 256 * 4);          // 51.2 MB
    unsigned short* kv1 = (unsigned short*)alloc((size_t)N * 256 * 2); // 25.6 MB
    float*          h1  = (float*)alloc((size_t)N * 128 * 4);          // 25.6 MB
    float*          qs2 = (float*)alloc((size_t)N * 64 * 4);           // 12.8 MB
    unsigned short* kv2 = (unsigned short*)alloc((size_t)N * 64 * 2);  //  6.4 MB
    int* row_ptr  = (int*)alloc((size_t)(N + 1) * 4);
    int* cnt      = (int*)alloc((size_t)N * 4);
    int* rank     = (int*)alloc((size_t)E * 4);
    int* colb     = (int*)alloc((size_t)E * 4);
    int* bsum     = (int*)alloc(64 * 4);
    int* boff     = (int*)alloc(64 * 4);

    int NBS = (N + 1023) / 1024; // 49 scan blocks

    k_zero<<<(N + 255) / 256, 256, 0, stream>>>(cnt, N);
    k_hist<<<(E + 255) / 256, 256, 0, stream>>>(dst, cnt, rank, E);
    k_scan1<<<NBS, 256, 0, stream>>>(cnt, row_ptr, bsum, N);
    k_scan2<<<1, 64, 0, stream>>>(bsum, boff, NBS);
    k_scan3<<<NBS, 256, 0, stream>>>(row_ptr, boff, N, E);
    k_scatter<<<(E + 255) / 256, 256, 0, stream>>>(src, dst, row_ptr, rank, colb, E);

    k_gemm1<<<(N + 63) / 64, 256, 0, stream>>>(x, Wq1, bq1, Wk1, bk1, Wv1, bv1, Ws1, bs1, qs1, kv1, N);
    k_agg1<<<(N + 3) / 4, 256, 0, stream>>>(qs1, (const unsigned int*)kv1, row_ptr, colb, h1, N);
    k_gemm2<<<(N + 63) / 64, 256, 0, stream>>>(h1, Wq2, bq2, Wk2, bk2, Wv2, bv2, Ws2, bs2, qs2, kv2, N);
    k_agg2<<<(N + 3) / 4, 256, 0, stream>>>(qs2, (const unsigned int*)kv2, row_ptr, colb, (float*)d_out, N);
}

// Round 4
// 223.263 us; speedup vs baseline: 1.7300x; 1.3025x over previous
//
#include <hip/hip_runtime.h>
#include <hip/hip_bf16.h>

#define N_NODES 50000
#define N_EDGES 800000

static constexpr float SCALE = 0.17677669529663687f; // 1/sqrt(32)

typedef __attribute__((ext_vector_type(8))) short bf16x8;
typedef __attribute__((ext_vector_type(4))) float f32x4;
#define MFMA16 __builtin_amdgcn_mfma_f32_16x16x32_bf16

static __device__ inline unsigned short f2bf(float f) {
    __hip_bfloat16 h = __float2bfloat16(f);
    return __builtin_bit_cast(unsigned short, h);
}
// unpack a packed pair of bf16 (one u32) -> two floats (x=low half, y=high half)
static __device__ inline float2 bfpair(unsigned u) {
    return make_float2(__uint_as_float(u << 16),
                       __uint_as_float(u & 0xffff0000u));
}

// ---------------- CSR construction ----------------

__global__ void k_zero(int* __restrict__ p, int n) {
    int i = blockIdx.x * 256 + threadIdx.x;
    if (i < n) p[i] = 0;
}

__global__ void k_hist(const int* __restrict__ dst, int* __restrict__ cnt,
                       int* __restrict__ rank, int E) {
    int e = blockIdx.x * 256 + threadIdx.x;
    if (e < E) rank[e] = atomicAdd(&cnt[dst[e]], 1);
}

__global__ __launch_bounds__(256) void k_scan1(const int* __restrict__ cnt,
                                               int* __restrict__ row,
                                               int* __restrict__ bsum, int n) {
    __shared__ int wsum[4];
    int t = threadIdx.x;
    int base = blockIdx.x * 1024 + t * 4;
    int v0 = (base + 0 < n) ? cnt[base + 0] : 0;
    int v1 = (base + 1 < n) ? cnt[base + 1] : 0;
    int v2 = (base + 2 < n) ? cnt[base + 2] : 0;
    int v3 = (base + 3 < n) ? cnt[base + 3] : 0;
    int s = v0 + v1 + v2 + v3;
    int lane = t & 63, wid = t >> 6;
    int sc = s;
#pragma unroll
    for (int d = 1; d < 64; d <<= 1) {
        int o = __shfl_up(sc, d);
        if (lane >= d) sc += o;
    }
    if (lane == 63) wsum[wid] = sc;
    __syncthreads();
    int woff = 0;
    for (int w = 0; w < wid; ++w) woff += wsum[w];
    int excl = woff + sc - s;
    if (base + 0 < n) row[base + 0] = excl;
    if (base + 1 < n) row[base + 1] = excl + v0;
    if (base + 2 < n) row[base + 2] = excl + v0 + v1;
    if (base + 3 < n) row[base + 3] = excl + v0 + v1 + v2;
    if (t == 255) bsum[blockIdx.x] = woff + sc;
}

__global__ void k_scan2(const int* __restrict__ bsum, int* __restrict__ boff, int nb) {
    int t = threadIdx.x; // 64 threads, single wave
    int v = (t < nb) ? bsum[t] : 0;
    int sc = v;
#pragma unroll
    for (int d = 1; d < 64; d <<= 1) {
        int o = __shfl_up(sc, d);
        if (t >= d) sc += o;
    }
    boff[t] = sc - v; // exclusive
}

__global__ void k_scan3(int* __restrict__ row, const int* __restrict__ boff,
                        int n, int total) {
    int t = threadIdx.x;
    int base = blockIdx.x * 1024 + t * 4;
    int o = boff[blockIdx.x];
#pragma unroll
    for (int r = 0; r < 4; ++r)
        if (base + r < n) row[base + r] += o;
    if (blockIdx.x == 0 && t == 0) row[n] = total;
}

__global__ void k_scatter(const int* __restrict__ src, const int* __restrict__ dst,
                          const int* __restrict__ row, const int* __restrict__ rank,
                          int* __restrict__ col, int E) {
    int e = blockIdx.x * 256 + threadIdx.x;
    if (e < E) col[row[dst[e]] + rank[e]] = src[e];
}

// ---------------- prep: x -> bf16 ----------------

__global__ void k_x2bf(const float* __restrict__ x, unsigned short* __restrict__ xb, int n4) {
    int i = blockIdx.x * 256 + threadIdx.x;
    if (i < n4) {
        float4 f = ((const float4*)x)[i];
        ushort4 u;
        u.x = f2bf(f.x); u.y = f2bf(f.y); u.z = f2bf(f.z); u.w = f2bf(f.w);
        ((ushort4*)xb)[i] = u;
    }
}

// ---------------- prep: pre-fragmented bf16 weights ----------------
// Fragment convention (consistent for A and B, so exact HW k-order is irrelevant):
//   lane l, elem j  <->  k = ks*32 + (l>>4)*8 + j ;  col = nt*16 + (l&15)
// Wf1: layer1, 4 mats [64][128]: flat id = (m*8+nt)*1024 + ks*512 + l*8 + j
// Wf2: layer2, 4 mats [128][32]: flat id = (g*4+ks)*512 + l*8 + j, g = m*2+t

__global__ void k_wfrag(
    const float* __restrict__ Wq1, const float* __restrict__ Wk1,
    const float* __restrict__ Wv1, const float* __restrict__ Ws1,
    const float* __restrict__ Wq2, const float* __restrict__ Wk2,
    const float* __restrict__ Wv2, const float* __restrict__ Ws2,
    unsigned short* __restrict__ Wf1, unsigned short* __restrict__ Wf2)
{
    int id = blockIdx.x * 256 + threadIdx.x;
    if (id < 32768) {
        int j = id & 7, l = (id >> 3) & 63, ks = (id >> 9) & 1, nt = (id >> 10) & 7, m = (id >> 13) & 3;
        const float* W = (m == 0) ? Wq1 : (m == 1) ? Wk1 : (m == 2) ? Wv1 : Ws1;
        int k = ks * 32 + ((l >> 4) << 3) + j;
        int c = nt * 16 + (l & 15);
        Wf1[id] = f2bf(W[k * 128 + c]);
    } else if (id < 49152) {
        int id2 = id - 32768;
        int j = id2 & 7, l = (id2 >> 3) & 63, ks = (id2 >> 9) & 3, g = (id2 >> 11) & 7;
        int m = g >> 1, t = g & 1;
        const float* W = (m == 0) ? Wq2 : (m == 1) ? Wk2 : (m == 2) ? Wv2 : Ws2;
        int k = ks * 32 + ((l >> 4) << 3) + j;
        int c = t * 16 + (l & 15);
        Wf2[id2] = f2bf(W[k * 32 + c]);
    }
}

// ---------------- GEMM 1 (MFMA): xb[N,64]bf16 @ {Wq,Wk,Wv,Ws}[64,128] + b ----------------
// block = 4 waves; wave w owns weight matrix w; 32 rows/block, 128 cols/wave.
// outputs: qs1[N][256] fp32 (q 0:128, s 128:256); kv1[N][256] bf16 (k 0:128, v 128:256)

__global__ __launch_bounds__(256) void k_gemm1m(
    const unsigned short* __restrict__ xb, const unsigned short* __restrict__ Wf1,
    const float* __restrict__ bq, const float* __restrict__ bk,
    const float* __restrict__ bv, const float* __restrict__ bs,
    float* __restrict__ qs1, unsigned short* __restrict__ kv1, int n)
{
    int w = threadIdx.x >> 6;
    int l = threadIdx.x & 63;
    int rb = blockIdx.x * 32;
    int lr = l & 15, lk = l >> 4;
    f32x4 acc[2][8];
#pragma unroll
    for (int mt = 0; mt < 2; ++mt)
#pragma unroll
        for (int nt = 0; nt < 8; ++nt) acc[mt][nt] = (f32x4){0.f, 0.f, 0.f, 0.f};
#pragma unroll
    for (int ks = 0; ks < 2; ++ks) {
        bf16x8 a[2];
#pragma unroll
        for (int mt = 0; mt < 2; ++mt) {
            int row = rb + mt * 16 + lr;
            if (row >= n) row = n - 1;
            a[mt] = *(const bf16x8*)(xb + (size_t)row * 64 + ks * 32 + lk * 8);
        }
#pragma unroll
        for (int nt = 0; nt < 8; ++nt) {
            bf16x8 b = *(const bf16x8*)(Wf1 + (size_t)((w * 8 + nt) * 1024 + ks * 512 + l * 8));
            acc[0][nt] = MFMA16(a[0], b, acc[0][nt], 0, 0, 0);
            acc[1][nt] = MFMA16(a[1], b, acc[1][nt], 0, 0, 0);
        }
    }
    const float* bptr = (w == 0) ? bq : (w == 1) ? bk : (w == 2) ? bv : bs;
#pragma unroll
    for (int nt = 0; nt < 8; ++nt) {
        int c = nt * 16 + lr;
        float bias = bptr[c];
#pragma unroll
        for (int mt = 0; mt < 2; ++mt) {
#pragma unroll
            for (int i = 0; i < 4; ++i) {
                int row = rb + mt * 16 + lk * 4 + i;
                if (row < n) {
                    float val = acc[mt][nt][i] + bias;
                    if (w == 0)      qs1[(size_t)row * 256 + c] = val;
                    else if (w == 3) qs1[(size_t)row * 256 + 128 + c] = val;
                    else if (w == 1) kv1[(size_t)row * 256 + c] = f2bf(val);
                    else             kv1[(size_t)row * 256 + 128 + c] = f2bf(val);
                }
            }
        }
    }
}

// ---------------- GEMM 2 (MFMA): h1b[N,128]bf16 @ {Wq,Wk,Wv,Ws}[128,32] + b ----------------
// block = 4 waves: wave = (row-half, col-half); 64 rows/block.
// outputs: qs2[N][64] fp32 (q 0:32, s 32:64); kv2[N][64] bf16 (k 0:32, v 32:64)

__global__ __launch_bounds__(256) void k_gemm2m(
    const unsigned short* __restrict__ h1b, const unsigned short* __restrict__ Wf2,
    const float* __restrict__ bq, const float* __restrict__ bk,
    const float* __restrict__ bv, const float* __restrict__ bs,
    float* __restrict__ qs2, unsigned short* __restrict__ kv2, int n)
{
    int w = threadIdx.x >> 6;
    int l = threadIdx.x & 63;
    int half = w & 1;
    int rb = blockIdx.x * 64 + (w >> 1) * 32;
    int lr = l & 15, lk = l >> 4;
    f32x4 acc[2][4];
#pragma unroll
    for (int mt = 0; mt < 2; ++mt)
#pragma unroll
        for (int nt = 0; nt < 4; ++nt) acc[mt][nt] = (f32x4){0.f, 0.f, 0.f, 0.f};
#pragma unroll
    for (int ks = 0; ks < 4; ++ks) {
        bf16x8 a[2];
#pragma unroll
        for (int mt = 0; mt < 2; ++mt) {
            int row = rb + mt * 16 + lr;
            if (row >= n) row = n - 1;
            a[mt] = *(const bf16x8*)(h1b + (size_t)row * 128 + ks * 32 + lk * 8);
        }
#pragma unroll
        for (int nt = 0; nt < 4; ++nt) {
            int g = half * 4 + nt;
            bf16x8 b = *(const bf16x8*)(Wf2 + (size_t)((g * 4 + ks) * 512 + l * 8));
            acc[0][nt] = MFMA16(a[0], b, acc[0][nt], 0, 0, 0);
            acc[1][nt] = MFMA16(a[1], b, acc[1][nt], 0, 0, 0);
        }
    }
#pragma unroll
    for (int nt = 0; nt < 4; ++nt) {
        int g = half * 4 + nt;
        int cg = g * 16 + lr;
        int mat = g >> 1;      // uniform per frag (mats are 32 cols, g*16 keeps pairs)
        int c = cg & 31;
        const float* bp = (mat == 0) ? bq : (mat == 1) ? bk : (mat == 2) ? bv : bs;
        float bias = bp[c];
#pragma unroll
        for (int mt = 0; mt < 2; ++mt) {
#pragma unroll
            for (int i = 0; i < 4; ++i) {
                int row = rb + mt * 16 + lk * 4 + i;
                if (row < n) {
                    float val = acc[mt][nt][i] + bias;
                    if (mat == 0)      qs2[(size_t)row * 64 + c] = val;
                    else if (mat == 3) qs2[(size_t)row * 64 + 32 + c] = val;
                    else if (mat == 1) kv2[(size_t)row * 64 + c] = f2bf(val);
                    else               kv2[(size_t)row * 64 + 32 + c] = f2bf(val);
                }
            }
        }
    }
}

// ---------------- Layer-1 attention aggregate ----------------
// one wave per dst node; lane l owns packed elements {2l, 2l+1} (one uint) of the
// 128-dim (h,c) flat; head h = l>>4 -> per-head dot reduces over 16-lane groups.
// Unrolled 4 edges/iteration for memory-level parallelism. Writes h1 as bf16.

__global__ __launch_bounds__(256) void k_agg1(
    const float* __restrict__ qs1, const unsigned int* __restrict__ kv1,
    const int* __restrict__ row_ptr, const int* __restrict__ col,
    unsigned int* __restrict__ h1b, int n)
{
    int i = blockIdx.x * 4 + (threadIdx.x >> 6);
    if (i >= n) return;
    int lane = threadIdx.x & 63;
    const float2 q = *(const float2*)&qs1[(size_t)i * 256 + 2 * lane];
    float ax = 0.f, ay = 0.f, d = 0.f;
    int s = row_ptr[i], e = row_ptr[i + 1];
    int t = s;
    for (; t + 4 <= e; t += 4) {
        int j0 = col[t], j1 = col[t + 1], j2 = col[t + 2], j3 = col[t + 3];
        const unsigned* p0 = kv1 + (size_t)j0 * 128;
        const unsigned* p1 = kv1 + (size_t)j1 * 128;
        const unsigned* p2 = kv1 + (size_t)j2 * 128;
        const unsigned* p3 = kv1 + (size_t)j3 * 128;
        unsigned ku0 = p0[lane],      ku1 = p1[lane],      ku2 = p2[lane],      ku3 = p3[lane];
        unsigned vu0 = p0[64 + lane], vu1 = p1[64 + lane], vu2 = p2[64 + lane], vu3 = p3[64 + lane];
        float2 k0 = bfpair(ku0), k1 = bfpair(ku1), k2 = bfpair(ku2), k3 = bfpair(ku3);
        float lg0 = q.x * k0.x + q.y * k0.y;
        float lg1 = q.x * k1.x + q.y * k1.y;
        float lg2 = q.x * k2.x + q.y * k2.y;
        float lg3 = q.x * k3.x + q.y * k3.y;
        lg0 += __shfl_xor(lg0, 1);  lg1 += __shfl_xor(lg1, 1);  lg2 += __shfl_xor(lg2, 1);  lg3 += __shfl_xor(lg3, 1);
        lg0 += __shfl_xor(lg0, 2);  lg1 += __shfl_xor(lg1, 2);  lg2 += __shfl_xor(lg2, 2);  lg3 += __shfl_xor(lg3, 2);
        lg0 += __shfl_xor(lg0, 4);  lg1 += __shfl_xor(lg1, 4);  lg2 += __shfl_xor(lg2, 4);  lg3 += __shfl_xor(lg3, 4);
        lg0 += __shfl_xor(lg0, 8);  lg1 += __shfl_xor(lg1, 8);  lg2 += __shfl_xor(lg2, 8);  lg3 += __shfl_xor(lg3, 8);
        float w0 = __expf(lg0 * SCALE), w1 = __expf(lg1 * SCALE);
        float w2 = __expf(lg2 * SCALE), w3 = __expf(lg3 * SCALE);
        float2 v0 = bfpair(vu0), v1 = bfpair(vu1), v2 = bfpair(vu2), v3 = bfpair(vu3);
        d  += (w0 + w1) + (w2 + w3);
        ax += w0 * v0.x + w1 * v1.x + w2 * v2.x + w3 * v3.x;
        ay += w0 * v0.y + w1 * v1.y + w2 * v2.y + w3 * v3.y;
    }
    for (; t < e; ++t) {
        int j = col[t];
        const unsigned* p = kv1 + (size_t)j * 128;
        unsigned ku = p[lane], vu = p[64 + lane];
        float2 kk = bfpair(ku);
        float lg = q.x * kk.x + q.y * kk.y;
        lg += __shfl_xor(lg, 1);
        lg += __shfl_xor(lg, 2);
        lg += __shfl_xor(lg, 4);
        lg += __shfl_xor(lg, 8);
        float w = __expf(lg * SCALE);
        float2 vv = bfpair(vu);
        d += w; ax += w * vv.x; ay += w * vv.y;
    }
    float rx = (d > 0.f) ? ax / d : 0.f;
    float ry = (d > 0.f) ? ay / d : 0.f;
    const float2 sv = *(const float2*)&qs1[(size_t)i * 256 + 128 + 2 * lane];
    rx += sv.x; ry += sv.y;
    rx = (rx > 0.f) ? rx : expm1f(rx); // ELU
    ry = (ry > 0.f) ? ry : expm1f(ry);
    unsigned pack = ((unsigned)f2bf(ry) << 16) | (unsigned)f2bf(rx);
    h1b[(size_t)i * 64 + lane] = pack;
}

// ---------------- Layer-2 attention aggregate ----------------
// one wave per dst node; 16-lane group g handles edges t+g and t+4+g (8 edges/iter);
// lane c=lane&15 owns channels {2c, 2c+1}.

__global__ __launch_bounds__(256) void k_agg2(
    const float* __restrict__ qs2, const unsigned int* __restrict__ kv2,
    const int* __restrict__ row_ptr, const int* __restrict__ col,
    float* __restrict__ out, int n)
{
    int i = blockIdx.x * 4 + (threadIdx.x >> 6);
    if (i >= n) return;
    int lane = threadIdx.x & 63;
    int g = lane >> 4, c = lane & 15;
    const float2 q = *(const float2*)&qs2[(size_t)i * 64 + 2 * c];
    float ax = 0.f, ay = 0.f, d = 0.f;
    int s = row_ptr[i], e = row_ptr[i + 1];
    for (int t = s; t < e; t += 8) {
        int t0 = t + g, t1 = t + 4 + g;
        bool va = t0 < e, vb = t1 < e;
        int j0 = col[va ? t0 : s];
        int j1 = col[vb ? t1 : s];
        const unsigned* p0 = kv2 + (size_t)j0 * 32;
        const unsigned* p1 = kv2 + (size_t)j1 * 32;
        unsigned ku0 = p0[c], vu0 = p0[16 + c];
        unsigned ku1 = p1[c], vu1 = p1[16 + c];
        float2 k0 = bfpair(ku0), k1 = bfpair(ku1);
        float lg0 = q.x * k0.x + q.y * k0.y;
        float lg1 = q.x * k1.x + q.y * k1.y;
        lg0 += __shfl_xor(lg0, 1);  lg1 += __shfl_xor(lg1, 1);
        lg0 += __shfl_xor(lg0, 2);  lg1 += __shfl_xor(lg1, 2);
        lg0 += __shfl_xor(lg0, 4);  lg1 += __shfl_xor(lg1, 4);
        lg0 += __shfl_xor(lg0, 8);  lg1 += __shfl_xor(lg1, 8);
        float w0 = va ? __expf(lg0 * SCALE) : 0.f;
        float w1 = vb ? __expf(lg1 * SCALE) : 0.f;
        float2 v0 = bfpair(vu0), v1 = bfpair(vu1);
        d += w0 + w1;
        ax += w0 * v0.x + w1 * v1.x;
        ay += w0 * v0.y + w1 * v1.y;
    }
    ax += __shfl_xor(ax, 16); ay += __shfl_xor(ay, 16); d += __shfl_xor(d, 16);
    ax += __shfl_xor(ax, 32); ay += __shfl_xor(ay, 32); d += __shfl_xor(d, 32);
    if (g == 0) {
        float rx = (d > 0.f) ? ax / d : 0.f;
        float ry = (d > 0.f) ? ay / d : 0.f;
        const float2 sv = *(const float2*)&qs2[(size_t)i * 64 + 32 + 2 * c];
        *(float2*)&out[(size_t)i * 32 + 2 * c] = make_float2(rx + sv.x, ry + sv.y);
    }
}

// ---------------- launch ----------------

extern "C" void kernel_launch(void* const* d_in, const int* in_sizes, int n_in,
                              void* d_out, int out_size, void* d_ws, size_t ws_size,
                              hipStream_t stream)
{
    const int N = N_NODES, E = N_EDGES;
    const float* x   = (const float*)d_in[0];
    const int* edge  = (const int*)d_in[1];
    const int* src   = edge;       // edge_index[0]
    const int* dst   = edge + E;   // edge_index[1]
    const float* Wq1 = (const float*)d_in[2];  const float* bq1 = (const float*)d_in[3];
    const float* Wk1 = (const float*)d_in[4];  const float* bk1 = (const float*)d_in[5];
    const float* Wv1 = (const float*)d_in[6];  const float* bv1 = (const float*)d_in[7];
    const float* Ws1 = (const float*)d_in[8];  const float* bs1 = (const float*)d_in[9];
    const float* Wq2 = (const float*)d_in[10]; const float* bq2 = (const float*)d_in[11];
    const float* Wk2 = (const float*)d_in[12]; const float* bk2 = (const float*)d_in[13];
    const float* Wv2 = (const float*)d_in[14]; const float* bv2 = (const float*)d_in[15];
    const float* Ws2 = (const float*)d_in[16]; const float* bs2 = (const float*)d_in[17];

    char* ws = (char*)d_ws;
    size_t off = 0;
    auto alloc = [&](size_t bytes) -> void* {
        void* p = ws + off;
        off += (bytes + 255) & ~(size_t)255;
        return p;
    };
    float*          qs1 = (float*)alloc((size_t)N * 256 * 4);          // 51.2 MB
    unsigned short* kv1 = (unsigned short*)alloc((size_t)N * 256 * 2); // 25.6 MB
    unsigned short* h1b = (unsigned short*)alloc((size_t)N * 128 * 2); // 12.8 MB
    float*          qs2 = (float*)alloc((size_t)N * 64 * 4);           // 12.8 MB
    unsigned short* kv2 = (unsigned short*)alloc((size_t)N * 64 * 2);  //  6.4 MB
    unsigned short* xb  = (unsigned short*)alloc((size_t)N * 64 * 2);  //  6.4 MB
    unsigned short* Wf1 = (unsigned short*)alloc(32768 * 2);
    unsigned short* Wf2 = (unsigned short*)alloc(16384 * 2);
    int* row_ptr  = (int*)alloc((size_t)(N + 1) * 4);
    int* cnt      = (int*)alloc((size_t)N * 4);
    int* rank     = (int*)alloc((size_t)E * 4);
    int* colb     = (int*)alloc((size_t)E * 4);
    int* bsum     = (int*)alloc(64 * 4);
    int* boff     = (int*)alloc(64 * 4);

    int NBS = (N + 1023) / 1024; // 49 scan blocks

    k_zero<<<(N + 255) / 256, 256, 0, stream>>>(cnt, N);
    k_hist<<<(E + 255) / 256, 256, 0, stream>>>(dst, cnt, rank, E);
    k_scan1<<<NBS, 256, 0, stream>>>(cnt, row_ptr, bsum, N);
    k_scan2<<<1, 64, 0, stream>>>(bsum, boff, NBS);
    k_scan3<<<NBS, 256, 0, stream>>>(row_ptr, boff, N, E);
    k_scatter<<<(E + 255) / 256, 256, 0, stream>>>(src, dst, row_ptr, rank, colb, E);

    k_x2bf<<<(N * 64 / 4 + 255) / 256, 256, 0, stream>>>(x, xb, N * 64 / 4);
    k_wfrag<<<192, 256, 0, stream>>>(Wq1, Wk1, Wv1, Ws1, Wq2, Wk2, Wv2, Ws2, Wf1, Wf2);

    k_gemm1m<<<(N + 31) / 32, 256, 0, stream>>>(xb, Wf1, bq1, bk1, bv1, bs1, qs1, kv1, N);
    k_agg1<<<(N + 3) / 4, 256, 0, stream>>>(qs1, (const unsigned int*)kv1, row_ptr, colb, (unsigned int*)h1b, N);
    k_gemm2m<<<(N + 63) / 64, 256, 0, stream>>>(h1b, Wf2, bq2, bk2, bv2, bs2, qs2, kv2, N);
    k_agg2<<<(N + 3) / 4, 256, 0, stream>>>(qs2, (const unsigned int*)kv2, row_ptr, colb, (float*)d_out, N);
}

// Round 5
// 201.548 us; speedup vs baseline: 1.9164x; 1.1077x over previous
//
#include <hip/hip_runtime.h>
#include <hip/hip_bf16.h>

#define N_NODES 50000
#define N_EDGES 800000

static constexpr float SCALE = 0.17677669529663687f; // 1/sqrt(32)

typedef __attribute__((ext_vector_type(8))) short bf16x8;
typedef __attribute__((ext_vector_type(4))) float f32x4;
#define MFMA16 __builtin_amdgcn_mfma_f32_16x16x32_bf16

static __device__ inline unsigned short f2bf(float f) {
    __hip_bfloat16 h = __float2bfloat16(f);
    return __builtin_bit_cast(unsigned short, h);
}
// unpack a packed pair of bf16 (one u32) -> two floats (x=low half, y=high half)
static __device__ inline float2 bfpair(unsigned u) {
    return make_float2(__uint_as_float(u << 16),
                       __uint_as_float(u & 0xffff0000u));
}
// dot of 8 local channels: q[8] . unpacked(u)
static __device__ inline float dot8(const float* q, uint4 u) {
    float2 a = bfpair(u.x), b = bfpair(u.y), c = bfpair(u.z), d = bfpair(u.w);
    return q[0]*a.x + q[1]*a.y + q[2]*b.x + q[3]*b.y
         + q[4]*c.x + q[5]*c.y + q[6]*d.x + q[7]*d.y;
}
static __device__ inline void acc8(float* acc, float w, uint4 u) {
    float2 a = bfpair(u.x), b = bfpair(u.y), c = bfpair(u.z), d = bfpair(u.w);
    acc[0] += w*a.x; acc[1] += w*a.y; acc[2] += w*b.x; acc[3] += w*b.y;
    acc[4] += w*c.x; acc[5] += w*c.y; acc[6] += w*d.x; acc[7] += w*d.y;
}
static __device__ inline void unpack8(float* o, uint4 u) {
    float2 a = bfpair(u.x), b = bfpair(u.y), c = bfpair(u.z), d = bfpair(u.w);
    o[0]=a.x; o[1]=a.y; o[2]=b.x; o[3]=b.y; o[4]=c.x; o[5]=c.y; o[6]=d.x; o[7]=d.y;
}

// ---------------- CSR construction ----------------

__global__ void k_hist(const int* __restrict__ dst, int* __restrict__ cnt,
                       int* __restrict__ rank, int E) {
    int e = blockIdx.x * 256 + threadIdx.x;
    if (e < E) rank[e] = atomicAdd(&cnt[dst[e]], 1);
}

__global__ __launch_bounds__(256) void k_scan1(const int* __restrict__ cnt,
                                               int* __restrict__ row,
                                               int* __restrict__ bsum, int n) {
    __shared__ int wsum[4];
    int t = threadIdx.x;
    int base = blockIdx.x * 1024 + t * 4;
    int v0 = (base + 0 < n) ? cnt[base + 0] : 0;
    int v1 = (base + 1 < n) ? cnt[base + 1] : 0;
    int v2 = (base + 2 < n) ? cnt[base + 2] : 0;
    int v3 = (base + 3 < n) ? cnt[base + 3] : 0;
    int s = v0 + v1 + v2 + v3;
    int lane = t & 63, wid = t >> 6;
    int sc = s;
#pragma unroll
    for (int d = 1; d < 64; d <<= 1) {
        int o = __shfl_up(sc, d);
        if (lane >= d) sc += o;
    }
    if (lane == 63) wsum[wid] = sc;
    __syncthreads();
    int woff = 0;
    for (int w = 0; w < wid; ++w) woff += wsum[w];
    int excl = woff + sc - s;
    if (base + 0 < n) row[base + 0] = excl;
    if (base + 1 < n) row[base + 1] = excl + v0;
    if (base + 2 < n) row[base + 2] = excl + v0 + v1;
    if (base + 3 < n) row[base + 3] = excl + v0 + v1 + v2;
    if (t == 255) bsum[blockIdx.x] = woff + sc;
}

__global__ void k_scan2(const int* __restrict__ bsum, int* __restrict__ boff, int nb) {
    int t = threadIdx.x; // 64 threads, single wave
    int v = (t < nb) ? bsum[t] : 0;
    int sc = v;
#pragma unroll
    for (int d = 1; d < 64; d <<= 1) {
        int o = __shfl_up(sc, d);
        if (t >= d) sc += o;
    }
    boff[t] = sc - v; // exclusive
}

__global__ void k_scan3(int* __restrict__ row, const int* __restrict__ boff,
                        int n, int total) {
    int t = threadIdx.x;
    int base = blockIdx.x * 1024 + t * 4;
    int o = boff[blockIdx.x];
#pragma unroll
    for (int r = 0; r < 4; ++r)
        if (base + r < n) row[base + r] += o;
    if (blockIdx.x == 0 && t == 0) row[n] = total;
}

__global__ void k_scatter(const int* __restrict__ src, const int* __restrict__ dst,
                          const int* __restrict__ row, const int* __restrict__ rank,
                          int* __restrict__ col, int E) {
    int e = blockIdx.x * 256 + threadIdx.x;
    if (e < E) col[row[dst[e]] + rank[e]] = src[e];
}

// ---------------- prep: x->bf16 (blocks 0..3124) + weight fragments (blocks 3125..) ----------------
// Fragment convention (consistent for A and B, so exact HW k-order is irrelevant):
//   lane l, elem j  <->  k = ks*32 + (l>>4)*8 + j ;  col = nt*16 + (l&15)

__global__ void k_prep(
    const float* __restrict__ x, unsigned short* __restrict__ xb,
    const float* __restrict__ Wq1, const float* __restrict__ Wk1,
    const float* __restrict__ Wv1, const float* __restrict__ Ws1,
    const float* __restrict__ Wq2, const float* __restrict__ Wk2,
    const float* __restrict__ Wv2, const float* __restrict__ Ws2,
    unsigned short* __restrict__ Wf1, unsigned short* __restrict__ Wf2)
{
    if (blockIdx.x < 3125) {
        int i = blockIdx.x * 256 + threadIdx.x; // < 800000 = N*64/4
        float4 f = ((const float4*)x)[i];
        ushort4 u;
        u.x = f2bf(f.x); u.y = f2bf(f.y); u.z = f2bf(f.z); u.w = f2bf(f.w);
        ((ushort4*)xb)[i] = u;
        return;
    }
    int id = (blockIdx.x - 3125) * 256 + threadIdx.x;
    if (id < 32768) {
        int j = id & 7, l = (id >> 3) & 63, ks = (id >> 9) & 1, nt = (id >> 10) & 7, m = (id >> 13) & 3;
        const float* W = (m == 0) ? Wq1 : (m == 1) ? Wk1 : (m == 2) ? Wv1 : Ws1;
        int k = ks * 32 + ((l >> 4) << 3) + j;
        int c = nt * 16 + (l & 15);
        Wf1[id] = f2bf(W[k * 128 + c]);
    } else if (id < 49152) {
        int id2 = id - 32768;
        int j = id2 & 7, l = (id2 >> 3) & 63, ks = (id2 >> 9) & 3, g = (id2 >> 11) & 7;
        int m = g >> 1, t = g & 1;
        const float* W = (m == 0) ? Wq2 : (m == 1) ? Wk2 : (m == 2) ? Wv2 : Ws2;
        int k = ks * 32 + ((l >> 4) << 3) + j;
        int c = t * 16 + (l & 15);
        Wf2[id2] = f2bf(W[k * 32 + c]);
    }
}

// ---------------- GEMM 1 (MFMA): xb[N,64]bf16 @ {Wq,Wk,Wv,Ws}[64,128] + b ----------------
// block = 4 waves; wave w owns weight matrix w; 32 rows/block.
// outputs (all bf16): qs1[N][256] (q 0:128, s 128:256); kv1[N][256] (k 0:128, v 128:256)

__global__ __launch_bounds__(256) void k_gemm1m(
    const unsigned short* __restrict__ xb, const unsigned short* __restrict__ Wf1,
    const float* __restrict__ bq, const float* __restrict__ bk,
    const float* __restrict__ bv, const float* __restrict__ bs,
    unsigned short* __restrict__ qs1, unsigned short* __restrict__ kv1, int n)
{
    int w = threadIdx.x >> 6;
    int l = threadIdx.x & 63;
    int rb = blockIdx.x * 32;
    int lr = l & 15, lk = l >> 4;
    f32x4 acc[2][8];
#pragma unroll
    for (int mt = 0; mt < 2; ++mt)
#pragma unroll
        for (int nt = 0; nt < 8; ++nt) acc[mt][nt] = (f32x4){0.f, 0.f, 0.f, 0.f};
#pragma unroll
    for (int ks = 0; ks < 2; ++ks) {
        bf16x8 a[2];
#pragma unroll
        for (int mt = 0; mt < 2; ++mt) {
            int row = rb + mt * 16 + lr;
            if (row >= n) row = n - 1;
            a[mt] = *(const bf16x8*)(xb + (size_t)row * 64 + ks * 32 + lk * 8);
        }
#pragma unroll
        for (int nt = 0; nt < 8; ++nt) {
            bf16x8 b = *(const bf16x8*)(Wf1 + (size_t)((w * 8 + nt) * 1024 + ks * 512 + l * 8));
            acc[0][nt] = MFMA16(a[0], b, acc[0][nt], 0, 0, 0);
            acc[1][nt] = MFMA16(a[1], b, acc[1][nt], 0, 0, 0);
        }
    }
    const float* bptr = (w == 0) ? bq : (w == 1) ? bk : (w == 2) ? bv : bs;
    unsigned short* outp = (w == 0) ? qs1 : (w == 3) ? qs1 + 128 : (w == 1) ? kv1 : kv1 + 128;
#pragma unroll
    for (int nt = 0; nt < 8; ++nt) {
        int c = nt * 16 + lr;
        float bias = bptr[c];
#pragma unroll
        for (int mt = 0; mt < 2; ++mt) {
#pragma unroll
            for (int i = 0; i < 4; ++i) {
                int row = rb + mt * 16 + lk * 4 + i;
                if (row < n)
                    outp[(size_t)row * 256 + c] = f2bf(acc[mt][nt][i] + bias);
            }
        }
    }
}

// ---------------- GEMM 2 (MFMA): h1b[N,128]bf16 @ {Wq,Wk,Wv,Ws}[128,32] + b ----------------
// block = 4 waves: wave = (row-half, col-half); 64 rows/block.
// outputs (all bf16): qs2[N][64] (q 0:32, s 32:64); kv2[N][64] (k 0:32, v 32:64)

__global__ __launch_bounds__(256) void k_gemm2m(
    const unsigned short* __restrict__ h1b, const unsigned short* __restrict__ Wf2,
    const float* __restrict__ bq, const float* __restrict__ bk,
    const float* __restrict__ bv, const float* __restrict__ bs,
    unsigned short* __restrict__ qs2, unsigned short* __restrict__ kv2, int n)
{
    int w = threadIdx.x >> 6;
    int l = threadIdx.x & 63;
    int half = w & 1;
    int rb = blockIdx.x * 64 + (w >> 1) * 32;
    int lr = l & 15, lk = l >> 4;
    f32x4 acc[2][4];
#pragma unroll
    for (int mt = 0; mt < 2; ++mt)
#pragma unroll
        for (int nt = 0; nt < 4; ++nt) acc[mt][nt] = (f32x4){0.f, 0.f, 0.f, 0.f};
#pragma unroll
    for (int ks = 0; ks < 4; ++ks) {
        bf16x8 a[2];
#pragma unroll
        for (int mt = 0; mt < 2; ++mt) {
            int row = rb + mt * 16 + lr;
            if (row >= n) row = n - 1;
            a[mt] = *(const bf16x8*)(h1b + (size_t)row * 128 + ks * 32 + lk * 8);
        }
#pragma unroll
        for (int nt = 0; nt < 4; ++nt) {
            int g = half * 4 + nt;
            bf16x8 b = *(const bf16x8*)(Wf2 + (size_t)((g * 4 + ks) * 512 + l * 8));
            acc[0][nt] = MFMA16(a[0], b, acc[0][nt], 0, 0, 0);
            acc[1][nt] = MFMA16(a[1], b, acc[1][nt], 0, 0, 0);
        }
    }
#pragma unroll
    for (int nt = 0; nt < 4; ++nt) {
        int g = half * 4 + nt;
        int mat = g >> 1;
        int c = (g * 16 + lr) & 31;
        const float* bp = (mat == 0) ? bq : (mat == 1) ? bk : (mat == 2) ? bv : bs;
        unsigned short* outp = (mat == 0) ? qs2 : (mat == 3) ? qs2 + 32
                             : (mat == 1) ? kv2 : kv2 + 32;
        float bias = bp[c];
#pragma unroll
        for (int mt = 0; mt < 2; ++mt) {
#pragma unroll
            for (int i = 0; i < 4; ++i) {
                int row = rb + mt * 16 + lk * 4 + i;
                if (row < n)
                    outp[(size_t)row * 64 + c] = f2bf(acc[mt][nt][i] + bias);
            }
        }
    }
}

// ---------------- Layer-1 attention aggregate ----------------
// one wave per dst node; lane = slot(0-3)*16 + w(0-15); lane owns channels [w*8, w*8+8).
// 8 edges per iteration (2 per slot). Per-edge dot reduces over 4 lanes (xor 1,2);
// cross-slot combine once per node (xor 16,32). All q/k/v/s bf16, accum fp32.

__global__ __launch_bounds__(256) void k_agg1(
    const unsigned short* __restrict__ qs1, const unsigned short* __restrict__ kv1,
    const int* __restrict__ row_ptr, const int* __restrict__ col,
    uint4* __restrict__ h1b, int n)
{
    int i = blockIdx.x * 4 + (threadIdx.x >> 6);
    if (i >= n) return;
    int lane = threadIdx.x & 63;
    int slot = lane >> 4, w = lane & 15;
    float q[8];
    unpack8(q, *(const uint4*)(qs1 + (size_t)i * 256 + w * 8));
    float acc[8] = {};
    float d = 0.f;
    int s = row_ptr[i], e = row_ptr[i + 1];
    for (int t = s; t < e; t += 8) {
        int ta = t + slot, tb = t + 4 + slot;
        bool va = ta < e, vb = tb < e;
        int ja = col[va ? ta : s];
        int jb = col[vb ? tb : s];
        const unsigned short* pa = kv1 + (size_t)ja * 256;
        const unsigned short* pb = kv1 + (size_t)jb * 256;
        uint4 ka = *(const uint4*)(pa + w * 8);
        uint4 kb = *(const uint4*)(pb + w * 8);
        uint4 vA = *(const uint4*)(pa + 128 + w * 8);
        uint4 vB = *(const uint4*)(pb + 128 + w * 8);
        float la = dot8(q, ka);
        float lb = dot8(q, kb);
        la += __shfl_xor(la, 1);  lb += __shfl_xor(lb, 1);
        la += __shfl_xor(la, 2);  lb += __shfl_xor(lb, 2);
        float wa = va ? __expf(la * SCALE) : 0.f;
        float wb = vb ? __expf(lb * SCALE) : 0.f;
        d += wa + wb;
        acc8(acc, wa, vA);
        acc8(acc, wb, vB);
    }
    // combine the 4 slots
#pragma unroll
    for (int m = 16; m <= 32; m <<= 1) {
        d += __shfl_xor(d, m);
#pragma unroll
        for (int c = 0; c < 8; ++c) acc[c] += __shfl_xor(acc[c], m);
    }
    if (slot == 0) {
        float inv = (d > 0.f) ? 1.f / d : 0.f;
        float sv[8];
        unpack8(sv, *(const uint4*)(qs1 + (size_t)i * 256 + 128 + w * 8));
        unsigned o[4];
#pragma unroll
        for (int p = 0; p < 4; ++p) {
            float rx = acc[2 * p] * inv + sv[2 * p];
            float ry = acc[2 * p + 1] * inv + sv[2 * p + 1];
            rx = (rx > 0.f) ? rx : expm1f(rx); // ELU
            ry = (ry > 0.f) ? ry : expm1f(ry);
            o[p] = ((unsigned)f2bf(ry) << 16) | (unsigned)f2bf(rx);
        }
        h1b[(size_t)i * 16 + w] = make_uint4(o[0], o[1], o[2], o[3]);
    }
}

// ---------------- Layer-2 attention aggregate ----------------
// one wave per dst node; lane = slot(0-15)*4 + qr(0-3); lane owns channels [qr*8, qr*8+8).
// 16 edges per iteration. Dot reduce xor 1,2; cross-slot combine xor 4..32.

__global__ __launch_bounds__(256) void k_agg2(
    const unsigned short* __restrict__ qs2, const unsigned short* __restrict__ kv2,
    const int* __restrict__ row_ptr, const int* __restrict__ col,
    float* __restrict__ out, int n)
{
    int i = blockIdx.x * 4 + (threadIdx.x >> 6);
    if (i >= n) return;
    int lane = threadIdx.x & 63;
    int slot = lane >> 2, qr = lane & 3;
    float q[8];
    unpack8(q, *(const uint4*)(qs2 + (size_t)i * 64 + qr * 8));
    float acc[8] = {};
    float d = 0.f;
    int s = row_ptr[i], e = row_ptr[i + 1];
    for (int t = s; t < e; t += 16) {
        int te = t + slot;
        bool va = te < e;
        int j = col[va ? te : s];
        const unsigned short* p = kv2 + (size_t)j * 64;
        uint4 ku = *(const uint4*)(p + qr * 8);
        uint4 vu = *(const uint4*)(p + 32 + qr * 8);
        float lg = dot8(q, ku);
        lg += __shfl_xor(lg, 1);
        lg += __shfl_xor(lg, 2);
        float wv = va ? __expf(lg * SCALE) : 0.f;
        d += wv;
        acc8(acc, wv, vu);
    }
#pragma unroll
    for (int m = 4; m <= 32; m <<= 1) {
        d += __shfl_xor(d, m);
#pragma unroll
        for (int c = 0; c < 8; ++c) acc[c] += __shfl_xor(acc[c], m);
    }
    if (slot == 0) {
        float inv = (d > 0.f) ? 1.f / d : 0.f;
        float sv[8];
        unpack8(sv, *(const uint4*)(qs2 + (size_t)i * 64 + 32 + qr * 8));
        float4 o0, o1;
        o0.x = acc[0] * inv + sv[0];
        o0.y = acc[1] * inv + sv[1];
        o0.z = acc[2] * inv + sv[2];
        o0.w = acc[3] * inv + sv[3];
        o1.x = acc[4] * inv + sv[4];
        o1.y = acc[5] * inv + sv[5];
        o1.z = acc[6] * inv + sv[6];
        o1.w = acc[7] * inv + sv[7];
        *(float4*)&out[(size_t)i * 32 + qr * 8] = o0;
        *(float4*)&out[(size_t)i * 32 + qr * 8 + 4] = o1;
    }
}

// ---------------- launch ----------------

extern "C" void kernel_launch(void* const* d_in, const int* in_sizes, int n_in,
                              void* d_out, int out_size, void* d_ws, size_t ws_size,
                              hipStream_t stream)
{
    const int N = N_NODES, E = N_EDGES;
    const float* x   = (const float*)d_in[0];
    const int* edge  = (const int*)d_in[1];
    const int* src   = edge;       // edge_index[0]
    const int* dst   = edge + E;   // edge_index[1]
    const float* Wq1 = (const float*)d_in[2];  const float* bq1 = (const float*)d_in[3];
    const float* Wk1 = (const float*)d_in[4];  const float* bk1 = (const float*)d_in[5];
    const float* Wv1 = (const float*)d_in[6];  const float* bv1 = (const float*)d_in[7];
    const float* Ws1 = (const float*)d_in[8];  const float* bs1 = (const float*)d_in[9];
    const float* Wq2 = (const float*)d_in[10]; const float* bq2 = (const float*)d_in[11];
    const float* Wk2 = (const float*)d_in[12]; const float* bk2 = (const float*)d_in[13];
    const float* Wv2 = (const float*)d_in[14]; const float* bv2 = (const float*)d_in[15];
    const float* Ws2 = (const float*)d_in[16]; const float* bs2 = (const float*)d_in[17];

    char* ws = (char*)d_ws;
    size_t off = 0;
    auto alloc = [&](size_t bytes) -> void* {
        void* p = ws + off;
        off += (bytes + 255) & ~(size_t)255;
        return p;
    };
    unsigned short* qs1 = (unsigned short*)alloc((size_t)N * 256 * 2); // 25.6 MB
    unsigned short* kv1 = (unsigned short*)alloc((size_t)N * 256 * 2); // 25.6 MB
    unsigned short* h1b = (unsigned short*)alloc((size_t)N * 128 * 2); // 12.8 MB
    unsigned short* qs2 = (unsigned short*)alloc((size_t)N * 64 * 2);  //  6.4 MB
    unsigned short* kv2 = (unsigned short*)alloc((size_t)N * 64 * 2);  //  6.4 MB
    unsigned short* xb  = (unsigned short*)alloc((size_t)N * 64 * 2);  //  6.4 MB
    unsigned short* Wf1 = (unsigned short*)alloc(32768 * 2);
    unsigned short* Wf2 = (unsigned short*)alloc(16384 * 2);
    int* row_ptr  = (int*)alloc((size_t)(N + 1) * 4);
    int* cnt      = (int*)alloc((size_t)N * 4);
    int* rank     = (int*)alloc((size_t)E * 4);
    int* colb     = (int*)alloc((size_t)E * 4);
    int* bsum     = (int*)alloc(64 * 4);
    int* boff     = (int*)alloc(64 * 4);

    int NBS = (N + 1023) / 1024; // 49 scan blocks

    hipMemsetAsync(cnt, 0, (size_t)N * 4, stream);
    k_hist<<<(E + 255) / 256, 256, 0, stream>>>(dst, cnt, rank, E);
    k_scan1<<<NBS, 256, 0, stream>>>(cnt, row_ptr, bsum, N);
    k_scan2<<<1, 64, 0, stream>>>(bsum, boff, NBS);
    k_scan3<<<NBS, 256, 0, stream>>>(row_ptr, boff, N, E);
    k_scatter<<<(E + 255) / 256, 256, 0, stream>>>(src, dst, row_ptr, rank, colb, E);

    k_prep<<<3125 + 192, 256, 0, stream>>>(x, xb, Wq1, Wk1, Wv1, Ws1,
                                           Wq2, Wk2, Wv2, Ws2, Wf1, Wf2);

    k_gemm1m<<<(N + 31) / 32, 256, 0, stream>>>(xb, Wf1, bq1, bk1, bv1, bs1, qs1, kv1, N);
    k_agg1<<<(N + 3) / 4, 256, 0, stream>>>(qs1, kv1, row_ptr, colb, (uint4*)h1b, N);
    k_gemm2m<<<(N + 63) / 64, 256, 0, stream>>>(h1b, Wf2, bq2, bk2, bv2, bs2, qs2, kv2, N);
    k_agg2<<<(N + 3) / 4, 256, 0, stream>>>(qs2, kv2, row_ptr, colb, (float*)d_out, N);
}

// Round 6
// 187.996 us; speedup vs baseline: 2.0545x; 1.0721x over previous
//
#include <hip/hip_runtime.h>
#include <hip/hip_bf16.h>

#define N_NODES 50000
#define N_EDGES 800000
#define HB 3125   // hist/scatter blocks: 800000/256
#define GB1 1563  // gemm1 blocks: ceil(50000/32)

static constexpr float SCALE = 0.17677669529663687f; // 1/sqrt(32)

typedef __attribute__((ext_vector_type(8))) short bf16x8;
typedef __attribute__((ext_vector_type(4))) float f32x4;
#define MFMA16 __builtin_amdgcn_mfma_f32_16x16x32_bf16

static __device__ inline unsigned short f2bf(float f) {
    __hip_bfloat16 h = __float2bfloat16(f);
    return __builtin_bit_cast(unsigned short, h);
}
static __device__ inline float2 bfpair(unsigned u) {
    return make_float2(__uint_as_float(u << 16),
                       __uint_as_float(u & 0xffff0000u));
}
static __device__ inline float dot8(const float* q, uint4 u) {
    float2 a = bfpair(u.x), b = bfpair(u.y), c = bfpair(u.z), d = bfpair(u.w);
    return q[0]*a.x + q[1]*a.y + q[2]*b.x + q[3]*b.y
         + q[4]*c.x + q[5]*c.y + q[6]*d.x + q[7]*d.y;
}
static __device__ inline void acc8(float* acc, float w, uint4 u) {
    float2 a = bfpair(u.x), b = bfpair(u.y), c = bfpair(u.z), d = bfpair(u.w);
    acc[0] += w*a.x; acc[1] += w*a.y; acc[2] += w*b.x; acc[3] += w*b.y;
    acc[4] += w*c.x; acc[5] += w*c.y; acc[6] += w*d.x; acc[7] += w*d.y;
}
static __device__ inline void unpack8(float* o, uint4 u) {
    float2 a = bfpair(u.x), b = bfpair(u.y), c = bfpair(u.z), d = bfpair(u.w);
    o[0]=a.x; o[1]=a.y; o[2]=b.x; o[3]=b.y; o[4]=c.x; o[5]=c.y; o[6]=d.x; o[7]=d.y;
}
// 8 contiguous f32 -> bf16x8 fragment
static __device__ inline bf16x8 cvt8(const float* p) {
    float4 f0 = *(const float4*)p;
    float4 f1 = *(const float4*)(p + 4);
    bf16x8 r;
    r[0] = (short)f2bf(f0.x); r[1] = (short)f2bf(f0.y);
    r[2] = (short)f2bf(f0.z); r[3] = (short)f2bf(f0.w);
    r[4] = (short)f2bf(f1.x); r[5] = (short)f2bf(f1.y);
    r[6] = (short)f2bf(f1.z); r[7] = (short)f2bf(f1.w);
    return r;
}

// ---------------- D1: hist (blocks 0..HB) + weight fragments (blocks HB..HB+192) ----------------
// Fragment convention (consistent for A and B, so exact HW k-order is irrelevant):
//   lane l, elem j  <->  k = ks*32 + (l>>4)*8 + j ;  col = nt*16 + (l&15)

__global__ __launch_bounds__(256) void k_heads(
    const int* __restrict__ dst, int* __restrict__ cnt, int* __restrict__ rank,
    const float* __restrict__ Wq1, const float* __restrict__ Wk1,
    const float* __restrict__ Wv1, const float* __restrict__ Ws1,
    const float* __restrict__ Wq2, const float* __restrict__ Wk2,
    const float* __restrict__ Wv2, const float* __restrict__ Ws2,
    unsigned short* __restrict__ Wf1, unsigned short* __restrict__ Wf2)
{
    if (blockIdx.x < HB) {
        int e = blockIdx.x * 256 + threadIdx.x; // E exact multiple of 256
        rank[e] = atomicAdd(&cnt[dst[e]], 1);
        return;
    }
    int id = (blockIdx.x - HB) * 256 + threadIdx.x;
    if (id < 32768) {
        int j = id & 7, l = (id >> 3) & 63, ks = (id >> 9) & 1, nt = (id >> 10) & 7, m = (id >> 13) & 3;
        const float* W = (m == 0) ? Wq1 : (m == 1) ? Wk1 : (m == 2) ? Wv1 : Ws1;
        int k = ks * 32 + ((l >> 4) << 3) + j;
        int c = nt * 16 + (l & 15);
        Wf1[id] = f2bf(W[k * 128 + c]);
    } else if (id < 49152) {
        int id2 = id - 32768;
        int j = id2 & 7, l = (id2 >> 3) & 63, ks = (id2 >> 9) & 3, g = (id2 >> 11) & 7;
        int m = g >> 1, t = g & 1;
        const float* W = (m == 0) ? Wq2 : (m == 1) ? Wk2 : (m == 2) ? Wv2 : Ws2;
        int k = ks * 32 + ((l >> 4) << 3) + j;
        int c = t * 16 + (l & 15);
        Wf2[id2] = f2bf(W[k * 32 + c]);
    }
}

// ---------------- scan over cnt -> row (block-local exclusive), bsum ----------------

__global__ __launch_bounds__(256) void k_scan1(const int* __restrict__ cnt,
                                               int* __restrict__ row,
                                               int* __restrict__ bsum, int n) {
    __shared__ int wsum[4];
    int t = threadIdx.x;
    int base = blockIdx.x * 1024 + t * 4;
    int v0 = (base + 0 < n) ? cnt[base + 0] : 0;
    int v1 = (base + 1 < n) ? cnt[base + 1] : 0;
    int v2 = (base + 2 < n) ? cnt[base + 2] : 0;
    int v3 = (base + 3 < n) ? cnt[base + 3] : 0;
    int s = v0 + v1 + v2 + v3;
    int lane = t & 63, wid = t >> 6;
    int sc = s;
#pragma unroll
    for (int d = 1; d < 64; d <<= 1) {
        int o = __shfl_up(sc, d);
        if (lane >= d) sc += o;
    }
    if (lane == 63) wsum[wid] = sc;
    __syncthreads();
    int woff = 0;
    for (int w = 0; w < wid; ++w) woff += wsum[w];
    int excl = woff + sc - s;
    if (base + 0 < n) row[base + 0] = excl;
    if (base + 1 < n) row[base + 1] = excl + v0;
    if (base + 2 < n) row[base + 2] = excl + v0 + v1;
    if (base + 3 < n) row[base + 3] = excl + v0 + v1 + v2;
    if (t == 255) bsum[blockIdx.x] = woff + sc;
}

// block-offset scan; also writes the row[N] fixup so rp(N) = E.
__global__ void k_scan2(const int* __restrict__ bsum, int* __restrict__ boff,
                        int* __restrict__ row, int nb) {
    int t = threadIdx.x; // 64 threads, single wave
    int v = (t < nb) ? bsum[t] : 0;
    int sc = v;
#pragma unroll
    for (int d = 1; d < 64; d <<= 1) {
        int o = __shfl_up(sc, d);
        if (t >= d) sc += o;
    }
    boff[t] = sc - v; // exclusive
    if (t == (N_NODES >> 10)) row[N_NODES] = N_EDGES - (sc - v);
}

// ---------------- D4: scatter (blocks 0..HB) + GEMM1 (blocks HB..HB+GB1) ----------------
// GEMM1 (MFMA): x[N,64]f32 (converted in-reg) @ {Wq,Wk,Wv,Ws}[64,128] + b
// 4 waves/block; wave w owns weight matrix w; 32 rows/block.
// outputs (all bf16): qs1[N][256] (q 0:128, s 128:256); kv1[N][256] (k 0:128, v 128:256)

__global__ __launch_bounds__(256) void k_work(
    const int* __restrict__ src, const int* __restrict__ dst,
    const int* __restrict__ row, const int* __restrict__ boff,
    const int* __restrict__ rank, int* __restrict__ col,
    const float* __restrict__ x, const unsigned short* __restrict__ Wf1,
    const float* __restrict__ bq, const float* __restrict__ bk,
    const float* __restrict__ bv, const float* __restrict__ bs,
    unsigned short* __restrict__ qs1, unsigned short* __restrict__ kv1, int n)
{
    if (blockIdx.x < HB) {
        int e = blockIdx.x * 256 + threadIdx.x;
        int de = dst[e];
        col[row[de] + boff[de >> 10] + rank[e]] = src[e];
        return;
    }
    int w = threadIdx.x >> 6;
    int l = threadIdx.x & 63;
    int rb = (blockIdx.x - HB) * 32;
    int lr = l & 15, lk = l >> 4;
    f32x4 acc[2][8];
#pragma unroll
    for (int mt = 0; mt < 2; ++mt)
#pragma unroll
        for (int nt = 0; nt < 8; ++nt) acc[mt][nt] = (f32x4){0.f, 0.f, 0.f, 0.f};
#pragma unroll
    for (int ks = 0; ks < 2; ++ks) {
        bf16x8 a[2];
#pragma unroll
        for (int mt = 0; mt < 2; ++mt) {
            int r = rb + mt * 16 + lr;
            if (r >= n) r = n - 1;
            a[mt] = cvt8(x + (size_t)r * 64 + ks * 32 + lk * 8);
        }
#pragma unroll
        for (int nt = 0; nt < 8; ++nt) {
            bf16x8 b = *(const bf16x8*)(Wf1 + (size_t)((w * 8 + nt) * 1024 + ks * 512 + l * 8));
            acc[0][nt] = MFMA16(a[0], b, acc[0][nt], 0, 0, 0);
            acc[1][nt] = MFMA16(a[1], b, acc[1][nt], 0, 0, 0);
        }
    }
    const float* bptr = (w == 0) ? bq : (w == 1) ? bk : (w == 2) ? bv : bs;
    unsigned short* outp = (w == 0) ? qs1 : (w == 3) ? qs1 + 128 : (w == 1) ? kv1 : kv1 + 128;
#pragma unroll
    for (int nt = 0; nt < 8; ++nt) {
        int c = nt * 16 + lr;
        float bias = bptr[c];
#pragma unroll
        for (int mt = 0; mt < 2; ++mt) {
#pragma unroll
            for (int i = 0; i < 4; ++i) {
                int r = rb + mt * 16 + lk * 4 + i;
                if (r < n)
                    outp[(size_t)r * 256 + c] = f2bf(acc[mt][nt][i] + bias);
            }
        }
    }
}

// ---------------- GEMM 2 (MFMA): h1b[N,128]bf16 @ {Wq,Wk,Wv,Ws}[128,32] + b ----------------

__global__ __launch_bounds__(256) void k_gemm2m(
    const unsigned short* __restrict__ h1b, const unsigned short* __restrict__ Wf2,
    const float* __restrict__ bq, const float* __restrict__ bk,
    const float* __restrict__ bv, const float* __restrict__ bs,
    unsigned short* __restrict__ qs2, unsigned short* __restrict__ kv2, int n)
{
    int w = threadIdx.x >> 6;
    int l = threadIdx.x & 63;
    int half = w & 1;
    int rb = blockIdx.x * 64 + (w >> 1) * 32;
    int lr = l & 15, lk = l >> 4;
    f32x4 acc[2][4];
#pragma unroll
    for (int mt = 0; mt < 2; ++mt)
#pragma unroll
        for (int nt = 0; nt < 4; ++nt) acc[mt][nt] = (f32x4){0.f, 0.f, 0.f, 0.f};
#pragma unroll
    for (int ks = 0; ks < 4; ++ks) {
        bf16x8 a[2];
#pragma unroll
        for (int mt = 0; mt < 2; ++mt) {
            int r = rb + mt * 16 + lr;
            if (r >= n) r = n - 1;
            a[mt] = *(const bf16x8*)(h1b + (size_t)r * 128 + ks * 32 + lk * 8);
        }
#pragma unroll
        for (int nt = 0; nt < 4; ++nt) {
            int g = half * 4 + nt;
            bf16x8 b = *(const bf16x8*)(Wf2 + (size_t)((g * 4 + ks) * 512 + l * 8));
            acc[0][nt] = MFMA16(a[0], b, acc[0][nt], 0, 0, 0);
            acc[1][nt] = MFMA16(a[1], b, acc[1][nt], 0, 0, 0);
        }
    }
#pragma unroll
    for (int nt = 0; nt < 4; ++nt) {
        int g = half * 4 + nt;
        int mat = g >> 1;
        int c = (g * 16 + lr) & 31;
        const float* bp = (mat == 0) ? bq : (mat == 1) ? bk : (mat == 2) ? bv : bs;
        unsigned short* outp = (mat == 0) ? qs2 : (mat == 3) ? qs2 + 32
                             : (mat == 1) ? kv2 : kv2 + 32;
        float bias = bp[c];
#pragma unroll
        for (int mt = 0; mt < 2; ++mt) {
#pragma unroll
            for (int i = 0; i < 4; ++i) {
                int r = rb + mt * 16 + lk * 4 + i;
                if (r < n)
                    outp[(size_t)r * 64 + c] = f2bf(acc[mt][nt][i] + bias);
            }
        }
    }
}

// ---------------- Layer-1 attention aggregate ----------------
// one wave per dst node; lane = slot(0-3)*16 + w(0-15); lane owns channels [w*8, w*8+8).
// 8 edges per iteration. row_ptr is block-local; add boff[i>>10] inline.

__global__ __launch_bounds__(256) void k_agg1(
    const unsigned short* __restrict__ qs1, const unsigned short* __restrict__ kv1,
    const int* __restrict__ row, const int* __restrict__ boff,
    const int* __restrict__ col, uint4* __restrict__ h1b, int n)
{
    int i = blockIdx.x * 4 + (threadIdx.x >> 6);
    if (i >= n) return;
    int lane = threadIdx.x & 63;
    int slot = lane >> 4, w = lane & 15;
    float q[8];
    unpack8(q, *(const uint4*)(qs1 + (size_t)i * 256 + w * 8));
    float acc[8] = {};
    float d = 0.f;
    int s = row[i] + boff[i >> 10];
    int e = row[i + 1] + boff[(i + 1) >> 10];
    for (int t = s; t < e; t += 8) {
        int ta = t + slot, tb = t + 4 + slot;
        bool va = ta < e, vb = tb < e;
        int ja = col[va ? ta : s];
        int jb = col[vb ? tb : s];
        const unsigned short* pa = kv1 + (size_t)ja * 256;
        const unsigned short* pb = kv1 + (size_t)jb * 256;
        uint4 ka = *(const uint4*)(pa + w * 8);
        uint4 kb = *(const uint4*)(pb + w * 8);
        uint4 vA = *(const uint4*)(pa + 128 + w * 8);
        uint4 vB = *(const uint4*)(pb + 128 + w * 8);
        float la = dot8(q, ka);
        float lb = dot8(q, kb);
        la += __shfl_xor(la, 1);  lb += __shfl_xor(lb, 1);
        la += __shfl_xor(la, 2);  lb += __shfl_xor(lb, 2);
        float wa = va ? __expf(la * SCALE) : 0.f;
        float wb = vb ? __expf(lb * SCALE) : 0.f;
        d += wa + wb;
        acc8(acc, wa, vA);
        acc8(acc, wb, vB);
    }
#pragma unroll
    for (int m = 16; m <= 32; m <<= 1) {
        d += __shfl_xor(d, m);
#pragma unroll
        for (int c = 0; c < 8; ++c) acc[c] += __shfl_xor(acc[c], m);
    }
    if (slot == 0) {
        float inv = (d > 0.f) ? 1.f / d : 0.f;
        float sv[8];
        unpack8(sv, *(const uint4*)(qs1 + (size_t)i * 256 + 128 + w * 8));
        unsigned o[4];
#pragma unroll
        for (int p = 0; p < 4; ++p) {
            float rx = acc[2 * p] * inv + sv[2 * p];
            float ry = acc[2 * p + 1] * inv + sv[2 * p + 1];
            rx = (rx > 0.f) ? rx : expm1f(rx); // ELU
            ry = (ry > 0.f) ? ry : expm1f(ry);
            o[p] = ((unsigned)f2bf(ry) << 16) | (unsigned)f2bf(rx);
        }
        h1b[(size_t)i * 16 + w] = make_uint4(o[0], o[1], o[2], o[3]);
    }
}

// ---------------- Layer-2 attention aggregate ----------------
// one wave per dst node; lane = slot(0-15)*4 + qr(0-3); 16 edges/iteration.

__global__ __launch_bounds__(256) void k_agg2(
    const unsigned short* __restrict__ qs2, const unsigned short* __restrict__ kv2,
    const int* __restrict__ row, const int* __restrict__ boff,
    const int* __restrict__ col, float* __restrict__ out, int n)
{
    int i = blockIdx.x * 4 + (threadIdx.x >> 6);
    if (i >= n) return;
    int lane = threadIdx.x & 63;
    int slot = lane >> 2, qr = lane & 3;
    float q[8];
    unpack8(q, *(const uint4*)(qs2 + (size_t)i * 64 + qr * 8));
    float acc[8] = {};
    float d = 0.f;
    int s = row[i] + boff[i >> 10];
    int e = row[i + 1] + boff[(i + 1) >> 10];
    for (int t = s; t < e; t += 16) {
        int te = t + slot;
        bool va = te < e;
        int j = col[va ? te : s];
        const unsigned short* p = kv2 + (size_t)j * 64;
        uint4 ku = *(const uint4*)(p + qr * 8);
        uint4 vu = *(const uint4*)(p + 32 + qr * 8);
        float lg = dot8(q, ku);
        lg += __shfl_xor(lg, 1);
        lg += __shfl_xor(lg, 2);
        float wv = va ? __expf(lg * SCALE) : 0.f;
        d += wv;
        acc8(acc, wv, vu);
    }
#pragma unroll
    for (int m = 4; m <= 32; m <<= 1) {
        d += __shfl_xor(d, m);
#pragma unroll
        for (int c = 0; c < 8; ++c) acc[c] += __shfl_xor(acc[c], m);
    }
    if (slot == 0) {
        float inv = (d > 0.f) ? 1.f / d : 0.f;
        float sv[8];
        unpack8(sv, *(const uint4*)(qs2 + (size_t)i * 64 + 32 + qr * 8));
        float4 o0, o1;
        o0.x = acc[0] * inv + sv[0];
        o0.y = acc[1] * inv + sv[1];
        o0.z = acc[2] * inv + sv[2];
        o0.w = acc[3] * inv + sv[3];
        o1.x = acc[4] * inv + sv[4];
        o1.y = acc[5] * inv + sv[5];
        o1.z = acc[6] * inv + sv[6];
        o1.w = acc[7] * inv + sv[7];
        *(float4*)&out[(size_t)i * 32 + qr * 8] = o0;
        *(float4*)&out[(size_t)i * 32 + qr * 8 + 4] = o1;
    }
}

// ---------------- launch ----------------

extern "C" void kernel_launch(void* const* d_in, const int* in_sizes, int n_in,
                              void* d_out, int out_size, void* d_ws, size_t ws_size,
                              hipStream_t stream)
{
    const int N = N_NODES, E = N_EDGES;
    const float* x   = (const float*)d_in[0];
    const int* edge  = (const int*)d_in[1];
    const int* src   = edge;       // edge_index[0]
    const int* dst   = edge + E;   // edge_index[1]
    const float* Wq1 = (const float*)d_in[2];  const float* bq1 = (const float*)d_in[3];
    const float* Wk1 = (const float*)d_in[4];  const float* bk1 = (const float*)d_in[5];
    const float* Wv1 = (const float*)d_in[6];  const float* bv1 = (const float*)d_in[7];
    const float* Ws1 = (const float*)d_in[8];  const float* bs1 = (const float*)d_in[9];
    const float* Wq2 = (const float*)d_in[10]; const float* bq2 = (const float*)d_in[11];
    const float* Wk2 = (const float*)d_in[12]; const float* bk2 = (const float*)d_in[13];
    const float* Wv2 = (const float*)d_in[14]; const float* bv2 = (const float*)d_in[15];
    const float* Ws2 = (const float*)d_in[16]; const float* bs2 = (const float*)d_in[17];

    char* ws = (char*)d_ws;
    size_t off = 0;
    auto alloc = [&](size_t bytes) -> void* {
        void* p = ws + off;
        off += (bytes + 255) & ~(size_t)255;
        return p;
    };
    unsigned short* qs1 = (unsigned short*)alloc((size_t)N * 256 * 2); // 25.6 MB
    unsigned short* kv1 = (unsigned short*)alloc((size_t)N * 256 * 2); // 25.6 MB
    unsigned short* h1b = (unsigned short*)alloc((size_t)N * 128 * 2); // 12.8 MB
    unsigned short* qs2 = (unsigned short*)alloc((size_t)N * 64 * 2);  //  6.4 MB
    unsigned short* kv2 = (unsigned short*)alloc((size_t)N * 64 * 2);  //  6.4 MB
    unsigned short* Wf1 = (unsigned short*)alloc(32768 * 2);
    unsigned short* Wf2 = (unsigned short*)alloc(16384 * 2);
    int* row_ptr  = (int*)alloc((size_t)(N + 1) * 4);
    int* cnt      = (int*)alloc((size_t)N * 4);
    int* rank     = (int*)alloc((size_t)E * 4);
    int* colb     = (int*)alloc((size_t)E * 4);
    int* bsum     = (int*)alloc(64 * 4);
    int* boff     = (int*)alloc(64 * 4);

    int NBS = (N + 1023) / 1024; // 49 scan blocks

    hipMemsetAsync(cnt, 0, (size_t)N * 4, stream);
    k_heads<<<HB + 192, 256, 0, stream>>>(dst, cnt, rank,
                                          Wq1, Wk1, Wv1, Ws1, Wq2, Wk2, Wv2, Ws2,
                                          Wf1, Wf2);
    k_scan1<<<NBS, 256, 0, stream>>>(cnt, row_ptr, bsum, N);
    k_scan2<<<1, 64, 0, stream>>>(bsum, boff, row_ptr, NBS);
    k_work<<<HB + GB1, 256, 0, stream>>>(src, dst, row_ptr, boff, rank, colb,
                                         x, Wf1, bq1, bk1, bv1, bs1, qs1, kv1, N);
    k_agg1<<<(N + 3) / 4, 256, 0, stream>>>(qs1, kv1, row_ptr, boff, colb, (uint4*)h1b, N);
    k_gemm2m<<<(N + 63) / 64, 256, 0, stream>>>(h1b, Wf2, bq2, bk2, bv2, bs2, qs2, kv2, N);
    k_agg2<<<(N + 3) / 4, 256, 0, stream>>>(qs2, kv2, row_ptr, boff, colb, (float*)d_out, N);
}

// Round 7
// 183.484 us; speedup vs baseline: 2.1051x; 1.0246x over previous
//
#include <hip/hip_runtime.h>
#include <hip/hip_bf16.h>
#include <hip/hip_fp8.h>

#define N_NODES 50000
#define N_EDGES 800000
#define HB 3125   // hist/scatter blocks: 800000/256
#define GB1 1563  // gemm1 blocks: ceil(50000/32)
#define NBS 49    // scan blocks: ceil(50000/1024)

static constexpr float SCALE = 0.17677669529663687f; // 1/sqrt(32)

typedef __attribute__((ext_vector_type(8))) short bf16x8;
typedef __attribute__((ext_vector_type(4))) float f32x4;
typedef __attribute__((ext_vector_type(2))) float f32x2;
#define MFMA16 __builtin_amdgcn_mfma_f32_16x16x32_bf16

static __device__ inline unsigned short f2bf(float f) {
    __hip_bfloat16 h = __float2bfloat16(f);
    return __builtin_bit_cast(unsigned short, h);
}
static __device__ inline unsigned char f2fp8(float f) {
    __hip_fp8_e4m3 h(f); // OCP e4m3fn, RNE
    return __builtin_bit_cast(unsigned char, h);
}
static __device__ inline float2 bfpair(unsigned u) {
    return make_float2(__uint_as_float(u << 16),
                       __uint_as_float(u & 0xffff0000u));
}
// q[8] . (8 fp8 values packed in uint2)
static __device__ inline float dot8f8(const float* q, uint2 u) {
    f32x2 a = __builtin_amdgcn_cvt_pk_f32_fp8(u.x, false);
    f32x2 b = __builtin_amdgcn_cvt_pk_f32_fp8(u.x, true);
    f32x2 c = __builtin_amdgcn_cvt_pk_f32_fp8(u.y, false);
    f32x2 d = __builtin_amdgcn_cvt_pk_f32_fp8(u.y, true);
    return q[0]*a[0] + q[1]*a[1] + q[2]*b[0] + q[3]*b[1]
         + q[4]*c[0] + q[5]*c[1] + q[6]*d[0] + q[7]*d[1];
}
// q[8] . (8 bf16 values packed in uint4)
static __device__ inline float dot8(const float* q, uint4 u) {
    float2 a = bfpair(u.x), b = bfpair(u.y), c = bfpair(u.z), d = bfpair(u.w);
    return q[0]*a.x + q[1]*a.y + q[2]*b.x + q[3]*b.y
         + q[4]*c.x + q[5]*c.y + q[6]*d.x + q[7]*d.y;
}
static __device__ inline void acc8(float* acc, float w, uint4 u) {
    float2 a = bfpair(u.x), b = bfpair(u.y), c = bfpair(u.z), d = bfpair(u.w);
    acc[0] += w*a.x; acc[1] += w*a.y; acc[2] += w*b.x; acc[3] += w*b.y;
    acc[4] += w*c.x; acc[5] += w*c.y; acc[6] += w*d.x; acc[7] += w*d.y;
}
static __device__ inline void unpack8(float* o, uint4 u) {
    float2 a = bfpair(u.x), b = bfpair(u.y), c = bfpair(u.z), d = bfpair(u.w);
    o[0]=a.x; o[1]=a.y; o[2]=b.x; o[3]=b.y; o[4]=c.x; o[5]=c.y; o[6]=d.x; o[7]=d.y;
}
static __device__ inline bf16x8 cvt8(const float* p) {
    float4 f0 = *(const float4*)p;
    float4 f1 = *(const float4*)(p + 4);
    bf16x8 r;
    r[0] = (short)f2bf(f0.x); r[1] = (short)f2bf(f0.y);
    r[2] = (short)f2bf(f0.z); r[3] = (short)f2bf(f0.w);
    r[4] = (short)f2bf(f1.x); r[5] = (short)f2bf(f1.y);
    r[6] = (short)f2bf(f1.z); r[7] = (short)f2bf(f1.w);
    return r;
}

// ---------------- D1: hist (blocks 0..HB) + weight fragments (blocks HB..HB+192) ----------------
// Fragment convention (consistent for A and B, so exact HW k-order is irrelevant):
//   lane l, elem j  <->  k = ks*32 + (l>>4)*8 + j ;  col = nt*16 + (l&15)

__global__ __launch_bounds__(256) void k_heads(
    const int* __restrict__ dst, int* __restrict__ cnt, int* __restrict__ rank,
    const float* __restrict__ Wq1, const float* __restrict__ Wk1,
    const float* __restrict__ Wv1, const float* __restrict__ Ws1,
    const float* __restrict__ Wq2, const float* __restrict__ Wk2,
    const float* __restrict__ Wv2, const float* __restrict__ Ws2,
    unsigned short* __restrict__ Wf1, unsigned short* __restrict__ Wf2)
{
    if (blockIdx.x < HB) {
        int e = blockIdx.x * 256 + threadIdx.x; // E exact multiple of 256
        rank[e] = atomicAdd(&cnt[dst[e]], 1);
        return;
    }
    int id = (blockIdx.x - HB) * 256 + threadIdx.x;
    if (id < 32768) {
        int j = id & 7, l = (id >> 3) & 63, ks = (id >> 9) & 1, nt = (id >> 10) & 7, m = (id >> 13) & 3;
        const float* W = (m == 0) ? Wq1 : (m == 1) ? Wk1 : (m == 2) ? Wv1 : Ws1;
        int k = ks * 32 + ((l >> 4) << 3) + j;
        int c = nt * 16 + (l & 15);
        Wf1[id] = f2bf(W[k * 128 + c]);
    } else if (id < 49152) {
        int id2 = id - 32768;
        int j = id2 & 7, l = (id2 >> 3) & 63, ks = (id2 >> 9) & 3, g = (id2 >> 11) & 7;
        int m = g >> 1, t = g & 1;
        const float* W = (m == 0) ? Wq2 : (m == 1) ? Wk2 : (m == 2) ? Wv2 : Ws2;
        int k = ks * 32 + ((l >> 4) << 3) + j;
        int c = t * 16 + (l & 15);
        Wf2[id2] = f2bf(W[k * 32 + c]);
    }
}

// ---------------- fused scan: block-local exclusive scan + last-block global offsets ----------------

__global__ __launch_bounds__(256) void k_scan(const int* __restrict__ cnt,
                                              int* __restrict__ row,
                                              int* __restrict__ bsum,
                                              int* __restrict__ boff,
                                              int* __restrict__ ctr, int n) {
    __shared__ int wsum[4];
    __shared__ int lastBlk;
    int t = threadIdx.x;
    int base = blockIdx.x * 1024 + t * 4;
    int v0 = (base + 0 < n) ? cnt[base + 0] : 0;
    int v1 = (base + 1 < n) ? cnt[base + 1] : 0;
    int v2 = (base + 2 < n) ? cnt[base + 2] : 0;
    int v3 = (base + 3 < n) ? cnt[base + 3] : 0;
    int s = v0 + v1 + v2 + v3;
    int lane = t & 63, wid = t >> 6;
    int sc = s;
#pragma unroll
    for (int d = 1; d < 64; d <<= 1) {
        int o = __shfl_up(sc, d);
        if (lane >= d) sc += o;
    }
    if (lane == 63) wsum[wid] = sc;
    __syncthreads();
    int woff = 0;
    for (int w = 0; w < wid; ++w) woff += wsum[w];
    int excl = woff + sc - s;
    if (base + 0 < n) row[base + 0] = excl;
    if (base + 1 < n) row[base + 1] = excl + v0;
    if (base + 2 < n) row[base + 2] = excl + v0 + v1;
    if (base + 3 < n) row[base + 3] = excl + v0 + v1 + v2;
    if (t == 255) {
        bsum[blockIdx.x] = woff + sc;
        __threadfence();
        lastBlk = (atomicAdd(ctr, 1) == (int)gridDim.x - 1);
    }
    __syncthreads();
    if (lastBlk && t < 64) {
        __threadfence();
        int v = (t < NBS) ? ((volatile int*)bsum)[t] : 0;
        int sc2 = v;
#pragma unroll
        for (int d = 1; d < 64; d <<= 1) {
            int o = __shfl_up(sc2, d);
            if (t >= d) sc2 += o;
        }
        boff[t] = sc2 - v; // exclusive block offset
        if (t == (N_NODES >> 10)) row[N_NODES] = N_EDGES - (sc2 - v);
    }
}

// ---------------- D4: scatter (blocks 0..HB) + GEMM1 (blocks HB..HB+GB1) ----------------
// GEMM1 (MFMA): x[N,64]f32 (converted in-reg) @ {Wq,Wk,Wv,Ws}[64,128] + b
// outputs: qs1[N][256] bf16 (q 0:128, s 128:256); k8[N][128] fp8-e4m3; v1[N][128] bf16

__global__ __launch_bounds__(256) void k_work(
    const int* __restrict__ src, const int* __restrict__ dst,
    const int* __restrict__ row, const int* __restrict__ boff,
    const int* __restrict__ rank, int* __restrict__ col,
    const float* __restrict__ x, const unsigned short* __restrict__ Wf1,
    const float* __restrict__ bq, const float* __restrict__ bk,
    const float* __restrict__ bv, const float* __restrict__ bs,
    unsigned short* __restrict__ qs1, unsigned char* __restrict__ k8,
    unsigned short* __restrict__ v1, int n)
{
    if (blockIdx.x < HB) {
        int e = blockIdx.x * 256 + threadIdx.x;
        int de = dst[e];
        col[row[de] + boff[de >> 10] + rank[e]] = src[e];
        return;
    }
    int w = threadIdx.x >> 6;
    int l = threadIdx.x & 63;
    int rb = (blockIdx.x - HB) * 32;
    int lr = l & 15, lk = l >> 4;
    f32x4 acc[2][8];
#pragma unroll
    for (int mt = 0; mt < 2; ++mt)
#pragma unroll
        for (int nt = 0; nt < 8; ++nt) acc[mt][nt] = (f32x4){0.f, 0.f, 0.f, 0.f};
#pragma unroll
    for (int ks = 0; ks < 2; ++ks) {
        bf16x8 a[2];
#pragma unroll
        for (int mt = 0; mt < 2; ++mt) {
            int r = rb + mt * 16 + lr;
            if (r >= n) r = n - 1;
            a[mt] = cvt8(x + (size_t)r * 64 + ks * 32 + lk * 8);
        }
#pragma unroll
        for (int nt = 0; nt < 8; ++nt) {
            bf16x8 b = *(const bf16x8*)(Wf1 + (size_t)((w * 8 + nt) * 1024 + ks * 512 + l * 8));
            acc[0][nt] = MFMA16(a[0], b, acc[0][nt], 0, 0, 0);
            acc[1][nt] = MFMA16(a[1], b, acc[1][nt], 0, 0, 0);
        }
    }
    const float* bptr = (w == 0) ? bq : (w == 1) ? bk : (w == 2) ? bv : bs;
    if (w == 1) { // k -> fp8, stride 128
#pragma unroll
        for (int nt = 0; nt < 8; ++nt) {
            int c = nt * 16 + lr;
            float bias = bptr[c];
#pragma unroll
            for (int mt = 0; mt < 2; ++mt)
#pragma unroll
                for (int i = 0; i < 4; ++i) {
                    int r = rb + mt * 16 + lk * 4 + i;
                    if (r < n) k8[(size_t)r * 128 + c] = f2fp8(acc[mt][nt][i] + bias);
                }
        }
    } else {
        unsigned short* outp = (w == 0) ? qs1 : (w == 3) ? qs1 + 128 : v1;
        size_t stride = (w == 2) ? 128 : 256;
#pragma unroll
        for (int nt = 0; nt < 8; ++nt) {
            int c = nt * 16 + lr;
            float bias = bptr[c];
#pragma unroll
            for (int mt = 0; mt < 2; ++mt)
#pragma unroll
                for (int i = 0; i < 4; ++i) {
                    int r = rb + mt * 16 + lk * 4 + i;
                    if (r < n) outp[(size_t)r * stride + c] = f2bf(acc[mt][nt][i] + bias);
                }
        }
    }
}

// ---------------- GEMM 2 (MFMA): h1b[N,128]bf16 @ {Wq,Wk,Wv,Ws}[128,32] + b ----------------

__global__ __launch_bounds__(256) void k_gemm2m(
    const unsigned short* __restrict__ h1b, const unsigned short* __restrict__ Wf2,
    const float* __restrict__ bq, const float* __restrict__ bk,
    const float* __restrict__ bv, const float* __restrict__ bs,
    unsigned short* __restrict__ qs2, unsigned short* __restrict__ kv2, int n)
{
    int w = threadIdx.x >> 6;
    int l = threadIdx.x & 63;
    int half = w & 1;
    int rb = blockIdx.x * 64 + (w >> 1) * 32;
    int lr = l & 15, lk = l >> 4;
    f32x4 acc[2][4];
#pragma unroll
    for (int mt = 0; mt < 2; ++mt)
#pragma unroll
        for (int nt = 0; nt < 4; ++nt) acc[mt][nt] = (f32x4){0.f, 0.f, 0.f, 0.f};
#pragma unroll
    for (int ks = 0; ks < 4; ++ks) {
        bf16x8 a[2];
#pragma unroll
        for (int mt = 0; mt < 2; ++mt) {
            int r = rb + mt * 16 + lr;
            if (r >= n) r = n - 1;
            a[mt] = *(const bf16x8*)(h1b + (size_t)r * 128 + ks * 32 + lk * 8);
        }
#pragma unroll
        for (int nt = 0; nt < 4; ++nt) {
            int g = half * 4 + nt;
            bf16x8 b = *(const bf16x8*)(Wf2 + (size_t)((g * 4 + ks) * 512 + l * 8));
            acc[0][nt] = MFMA16(a[0], b, acc[0][nt], 0, 0, 0);
            acc[1][nt] = MFMA16(a[1], b, acc[1][nt], 0, 0, 0);
        }
    }
#pragma unroll
    for (int nt = 0; nt < 4; ++nt) {
        int g = half * 4 + nt;
        int mat = g >> 1;
        int c = (g * 16 + lr) & 31;
        const float* bp = (mat == 0) ? bq : (mat == 1) ? bk : (mat == 2) ? bv : bs;
        unsigned short* outp = (mat == 0) ? qs2 : (mat == 3) ? qs2 + 32
                             : (mat == 1) ? kv2 : kv2 + 32;
        float bias = bp[c];
#pragma unroll
        for (int mt = 0; mt < 2; ++mt) {
#pragma unroll
            for (int i = 0; i < 4; ++i) {
                int r = rb + mt * 16 + lk * 4 + i;
                if (r < n)
                    outp[(size_t)r * 64 + c] = f2bf(acc[mt][nt][i] + bias);
            }
        }
    }
}

// ---------------- Layer-1 attention aggregate ----------------
// one wave per dst node; lane = slot(0-3)*16 + w(0-15); lane owns channels [w*8, w*8+8).
// 8 edges per iteration. k gathered as fp8 (8B/lane), v as bf16 (16B/lane).
// head h = w>>2 -> per-head dot reduces over 4 lanes (xor 1,2).

__global__ __launch_bounds__(256) void k_agg1(
    const unsigned short* __restrict__ qs1, const unsigned char* __restrict__ k8,
    const unsigned short* __restrict__ v1,
    const int* __restrict__ row, const int* __restrict__ boff,
    const int* __restrict__ col, uint4* __restrict__ h1b, int n)
{
    int i = blockIdx.x * 4 + (threadIdx.x >> 6);
    if (i >= n) return;
    int lane = threadIdx.x & 63;
    int slot = lane >> 4, w = lane & 15;
    float q[8];
    unpack8(q, *(const uint4*)(qs1 + (size_t)i * 256 + w * 8));
    float acc[8] = {};
    float d = 0.f;
    int s = row[i] + boff[i >> 10];
    int e = row[i + 1] + boff[(i + 1) >> 10];
    for (int t = s; t < e; t += 8) {
        int ta = t + slot, tb = t + 4 + slot;
        bool va = ta < e, vb = tb < e;
        int ja = col[va ? ta : s];
        int jb = col[vb ? tb : s];
        uint2 ka = *(const uint2*)(k8 + (size_t)ja * 128 + w * 8);
        uint2 kb = *(const uint2*)(k8 + (size_t)jb * 128 + w * 8);
        uint4 vA = *(const uint4*)(v1 + (size_t)ja * 128 + w * 8);
        uint4 vB = *(const uint4*)(v1 + (size_t)jb * 128 + w * 8);
        float la = dot8f8(q, ka);
        float lb = dot8f8(q, kb);
        la += __shfl_xor(la, 1);  lb += __shfl_xor(lb, 1);
        la += __shfl_xor(la, 2);  lb += __shfl_xor(lb, 2);
        float wa = va ? __expf(la * SCALE) : 0.f;
        float wb = vb ? __expf(lb * SCALE) : 0.f;
        d += wa + wb;
        acc8(acc, wa, vA);
        acc8(acc, wb, vB);
    }
#pragma unroll
    for (int m = 16; m <= 32; m <<= 1) {
        d += __shfl_xor(d, m);
#pragma unroll
        for (int c = 0; c < 8; ++c) acc[c] += __shfl_xor(acc[c], m);
    }
    if (slot == 0) {
        float inv = (d > 0.f) ? 1.f / d : 0.f;
        float sv[8];
        unpack8(sv, *(const uint4*)(qs1 + (size_t)i * 256 + 128 + w * 8));
        unsigned o[4];
#pragma unroll
        for (int p = 0; p < 4; ++p) {
            float rx = acc[2 * p] * inv + sv[2 * p];
            float ry = acc[2 * p + 1] * inv + sv[2 * p + 1];
            rx = (rx > 0.f) ? rx : expm1f(rx); // ELU
            ry = (ry > 0.f) ? ry : expm1f(ry);
            o[p] = ((unsigned)f2bf(ry) << 16) | (unsigned)f2bf(rx);
        }
        h1b[(size_t)i * 16 + w] = make_uint4(o[0], o[1], o[2], o[3]);
    }
}

// ---------------- Layer-2 attention aggregate ----------------
// one wave per dst node; lane = slot(0-15)*4 + qr(0-3); 16 edges/iteration.

__global__ __launch_bounds__(256) void k_agg2(
    const unsigned short* __restrict__ qs2, const unsigned short* __restrict__ kv2,
    const int* __restrict__ row, const int* __restrict__ boff,
    const int* __restrict__ col, float* __restrict__ out, int n)
{
    int i = blockIdx.x * 4 + (threadIdx.x >> 6);
    if (i >= n) return;
    int lane = threadIdx.x & 63;
    int slot = lane >> 2, qr = lane & 3;
    float q[8];
    unpack8(q, *(const uint4*)(qs2 + (size_t)i * 64 + qr * 8));
    float acc[8] = {};
    float d = 0.f;
    int s = row[i] + boff[i >> 10];
    int e = row[i + 1] + boff[(i + 1) >> 10];
    for (int t = s; t < e; t += 16) {
        int te = t + slot;
        bool va = te < e;
        int j = col[va ? te : s];
        const unsigned short* p = kv2 + (size_t)j * 64;
        uint4 ku = *(const uint4*)(p + qr * 8);
        uint4 vu = *(const uint4*)(p + 32 + qr * 8);
        float lg = dot8(q, ku);
        lg += __shfl_xor(lg, 1);
        lg += __shfl_xor(lg, 2);
        float wv = va ? __expf(lg * SCALE) : 0.f;
        d += wv;
        acc8(acc, wv, vu);
    }
#pragma unroll
    for (int m = 4; m <= 32; m <<= 1) {
        d += __shfl_xor(d, m);
#pragma unroll
        for (int c = 0; c < 8; ++c) acc[c] += __shfl_xor(acc[c], m);
    }
    if (slot == 0) {
        float inv = (d > 0.f) ? 1.f / d : 0.f;
        float sv[8];
        unpack8(sv, *(const uint4*)(qs2 + (size_t)i * 64 + 32 + qr * 8));
        float4 o0, o1;
        o0.x = acc[0] * inv + sv[0];
        o0.y = acc[1] * inv + sv[1];
        o0.z = acc[2] * inv + sv[2];
        o0.w = acc[3] * inv + sv[3];
        o1.x = acc[4] * inv + sv[4];
        o1.y = acc[5] * inv + sv[5];
        o1.z = acc[6] * inv + sv[6];
        o1.w = acc[7] * inv + sv[7];
        *(float4*)&out[(size_t)i * 32 + qr * 8] = o0;
        *(float4*)&out[(size_t)i * 32 + qr * 8 + 4] = o1;
    }
}

// ---------------- launch ----------------

extern "C" void kernel_launch(void* const* d_in, const int* in_sizes, int n_in,
                              void* d_out, int out_size, void* d_ws, size_t ws_size,
                              hipStream_t stream)
{
    const int N = N_NODES, E = N_EDGES;
    const float* x   = (const float*)d_in[0];
    const int* edge  = (const int*)d_in[1];
    const int* src   = edge;       // edge_index[0]
    const int* dst   = edge + E;   // edge_index[1]
    const float* Wq1 = (const float*)d_in[2];  const float* bq1 = (const float*)d_in[3];
    const float* Wk1 = (const float*)d_in[4];  const float* bk1 = (const float*)d_in[5];
    const float* Wv1 = (const float*)d_in[6];  const float* bv1 = (const float*)d_in[7];
    const float* Ws1 = (const float*)d_in[8];  const float* bs1 = (const float*)d_in[9];
    const float* Wq2 = (const float*)d_in[10]; const float* bq2 = (const float*)d_in[11];
    const float* Wk2 = (const float*)d_in[12]; const float* bk2 = (const float*)d_in[13];
    const float* Wv2 = (const float*)d_in[14]; const float* bv2 = (const float*)d_in[15];
    const float* Ws2 = (const float*)d_in[16]; const float* bs2 = (const float*)d_in[17];

    char* ws = (char*)d_ws;
    size_t off = 0;
    auto alloc = [&](size_t bytes) -> void* {
        void* p = ws + off;
        off += (bytes + 255) & ~(size_t)255;
        return p;
    };
    unsigned short* qs1 = (unsigned short*)alloc((size_t)N * 256 * 2); // 25.6 MB
    unsigned char*  k8  = (unsigned char*)alloc((size_t)N * 128);      //  6.4 MB
    unsigned short* v1  = (unsigned short*)alloc((size_t)N * 128 * 2); // 12.8 MB
    unsigned short* h1b = (unsigned short*)alloc((size_t)N * 128 * 2); // 12.8 MB
    unsigned short* qs2 = (unsigned short*)alloc((size_t)N * 64 * 2);  //  6.4 MB
    unsigned short* kv2 = (unsigned short*)alloc((size_t)N * 64 * 2);  //  6.4 MB
    unsigned short* Wf1 = (unsigned short*)alloc(32768 * 2);
    unsigned short* Wf2 = (unsigned short*)alloc(16384 * 2);
    int* row_ptr  = (int*)alloc((size_t)(N + 1) * 4);
    int* cnt      = (int*)alloc((size_t)(N + 64) * 4); // cnt[N] + ctr
    int* ctr      = cnt + N;
    int* rank     = (int*)alloc((size_t)E * 4);
    int* colb     = (int*)alloc((size_t)E * 4);
    int* bsum     = (int*)alloc(64 * 4);
    int* boff     = (int*)alloc(64 * 4);

    hipMemsetAsync(cnt, 0, (size_t)(N + 64) * 4, stream);
    k_heads<<<HB + 192, 256, 0, stream>>>(dst, cnt, rank,
                                          Wq1, Wk1, Wv1, Ws1, Wq2, Wk2, Wv2, Ws2,
                                          Wf1, Wf2);
    k_scan<<<NBS, 256, 0, stream>>>(cnt, row_ptr, bsum, boff, ctr, N);
    k_work<<<HB + GB1, 256, 0, stream>>>(src, dst, row_ptr, boff, rank, colb,
                                         x, Wf1, bq1, bk1, bv1, bs1, qs1, k8, v1, N);
    k_agg1<<<(N + 3) / 4, 256, 0, stream>>>(qs1, k8, v1, row_ptr, boff, colb, (uint4*)h1b, N);
    k_gemm2m<<<(N + 63) / 64, 256, 0, stream>>>(h1b, Wf2, bq2, bk2, bv2, bs2, qs2, kv2, N);
    k_agg2<<<(N + 3) / 4, 256, 0, stream>>>(qs2, kv2, row_ptr, boff, colb, (float*)d_out, N);
}

// Round 8
// 162.684 us; speedup vs baseline: 2.3742x; 1.1279x over previous
//
#include <hip/hip_runtime.h>
#include <hip/hip_bf16.h>
#include <hip/hip_fp8.h>

#define N_NODES 50000
#define N_EDGES 800000
#define HB 3125   // hist/scatter blocks: 800000/256
#define GB1 1563  // gemm1 blocks: ceil(50000/32)
#define NBS 49    // scan blocks: ceil(50000/1024)

static constexpr float SCALE = 0.17677669529663687f; // 1/sqrt(32)

typedef __attribute__((ext_vector_type(8))) short bf16x8;
typedef __attribute__((ext_vector_type(4))) float f32x4;
typedef __attribute__((ext_vector_type(2))) float f32x2;
#define MFMA16 __builtin_amdgcn_mfma_f32_16x16x32_bf16

static __device__ inline unsigned short f2bf(float f) {
    __hip_bfloat16 h = __float2bfloat16(f);
    return __builtin_bit_cast(unsigned short, h);
}
static __device__ inline unsigned char f2fp8(float f) {
    __hip_fp8_e4m3 h(f); // OCP e4m3fn, RNE
    return __builtin_bit_cast(unsigned char, h);
}
static __device__ inline float2 bfpair(unsigned u) {
    return make_float2(__uint_as_float(u << 16),
                       __uint_as_float(u & 0xffff0000u));
}
static __device__ inline float dot8f8(const float* q, uint2 u) {
    f32x2 a = __builtin_amdgcn_cvt_pk_f32_fp8(u.x, false);
    f32x2 b = __builtin_amdgcn_cvt_pk_f32_fp8(u.x, true);
    f32x2 c = __builtin_amdgcn_cvt_pk_f32_fp8(u.y, false);
    f32x2 d = __builtin_amdgcn_cvt_pk_f32_fp8(u.y, true);
    return q[0]*a[0] + q[1]*a[1] + q[2]*b[0] + q[3]*b[1]
         + q[4]*c[0] + q[5]*c[1] + q[6]*d[0] + q[7]*d[1];
}
static __device__ inline float dot8(const float* q, uint4 u) {
    float2 a = bfpair(u.x), b = bfpair(u.y), c = bfpair(u.z), d = bfpair(u.w);
    return q[0]*a.x + q[1]*a.y + q[2]*b.x + q[3]*b.y
         + q[4]*c.x + q[5]*c.y + q[6]*d.x + q[7]*d.y;
}
static __device__ inline void acc8(float* acc, float w, uint4 u) {
    float2 a = bfpair(u.x), b = bfpair(u.y), c = bfpair(u.z), d = bfpair(u.w);
    acc[0] += w*a.x; acc[1] += w*a.y; acc[2] += w*b.x; acc[3] += w*b.y;
    acc[4] += w*c.x; acc[5] += w*c.y; acc[6] += w*d.x; acc[7] += w*d.y;
}
static __device__ inline void unpack8(float* o, uint4 u) {
    float2 a = bfpair(u.x), b = bfpair(u.y), c = bfpair(u.z), d = bfpair(u.w);
    o[0]=a.x; o[1]=a.y; o[2]=b.x; o[3]=b.y; o[4]=c.x; o[5]=c.y; o[6]=d.x; o[7]=d.y;
}
static __device__ inline bf16x8 cvt8(const float* p) {
    float4 f0 = *(const float4*)p;
    float4 f1 = *(const float4*)(p + 4);
    bf16x8 r;
    r[0] = (short)f2bf(f0.x); r[1] = (short)f2bf(f0.y);
    r[2] = (short)f2bf(f0.z); r[3] = (short)f2bf(f0.w);
    r[4] = (short)f2bf(f1.x); r[5] = (short)f2bf(f1.y);
    r[6] = (short)f2bf(f1.z); r[7] = (short)f2bf(f1.w);
    return r;
}

// ---------------- D1: weight fragments ----------------
// Fragment convention (consistent for A and B, so exact HW k-order is irrelevant):
//   lane l, elem j  <->  k = ks*32 + (l>>4)*8 + j ;  col = nt*16 + (l&15)

__global__ __launch_bounds__(256) void k_prep(
    const float* __restrict__ Wq1, const float* __restrict__ Wk1,
    const float* __restrict__ Wv1, const float* __restrict__ Ws1,
    const float* __restrict__ Wq2, const float* __restrict__ Wk2,
    const float* __restrict__ Wv2, const float* __restrict__ Ws2,
    unsigned short* __restrict__ Wf1, unsigned short* __restrict__ Wf2)
{
    int id = blockIdx.x * 256 + threadIdx.x;
    if (id < 32768) {
        int j = id & 7, l = (id >> 3) & 63, ks = (id >> 9) & 1, nt = (id >> 10) & 7, m = (id >> 13) & 3;
        const float* W = (m == 0) ? Wq1 : (m == 1) ? Wk1 : (m == 2) ? Wv1 : Ws1;
        int k = ks * 32 + ((l >> 4) << 3) + j;
        int c = nt * 16 + (l & 15);
        Wf1[id] = f2bf(W[k * 128 + c]);
    } else if (id < 49152) {
        int id2 = id - 32768;
        int j = id2 & 7, l = (id2 >> 3) & 63, ks = (id2 >> 9) & 3, g = (id2 >> 11) & 7;
        int m = g >> 1, t = g & 1;
        const float* W = (m == 0) ? Wq2 : (m == 1) ? Wk2 : (m == 2) ? Wv2 : Ws2;
        int k = ks * 32 + ((l >> 4) << 3) + j;
        int c = t * 16 + (l & 15);
        Wf2[id2] = f2bf(W[k * 32 + c]);
    }
}

// ---------------- D2: GEMM1 (blocks 0..GB1) || hist (blocks GB1..GB1+HB) ----------------
// GEMM1 (MFMA): x[N,64]f32 (converted in-reg) @ {Wq,Wk,Wv,Ws}[64,128] + b
// outputs: qs1[N][256] bf16 (q 0:128, s 128:256); k8[N][128] fp8-e4m3; v1[N][128] bf16
// Epilogue staged through LDS so all global stores are full-line coalesced.

__global__ __launch_bounds__(256) void k_big(
    const int* __restrict__ dst, int* __restrict__ cnt, int* __restrict__ rank,
    const float* __restrict__ x, const unsigned short* __restrict__ Wf1,
    const float* __restrict__ bq, const float* __restrict__ bk,
    const float* __restrict__ bv, const float* __restrict__ bs,
    unsigned short* __restrict__ qs1, unsigned char* __restrict__ k8,
    unsigned short* __restrict__ v1, int n)
{
    __shared__ unsigned char smem[4 * 8704]; // per-wave 8704B: bf16 [32][136] or fp8 [32][144]
    if (blockIdx.x >= GB1) { // histogram half
        int e = (blockIdx.x - GB1) * 256 + threadIdx.x; // E multiple of 256
        rank[e] = atomicAdd(&cnt[dst[e]], 1);
        return;
    }
    int w = threadIdx.x >> 6;
    int l = threadIdx.x & 63;
    int rb = blockIdx.x * 32;
    int lr = l & 15, lk = l >> 4;
    f32x4 acc[2][8];
#pragma unroll
    for (int mt = 0; mt < 2; ++mt)
#pragma unroll
        for (int nt = 0; nt < 8; ++nt) acc[mt][nt] = (f32x4){0.f, 0.f, 0.f, 0.f};
#pragma unroll
    for (int ks = 0; ks < 2; ++ks) {
        bf16x8 a[2];
#pragma unroll
        for (int mt = 0; mt < 2; ++mt) {
            int r = rb + mt * 16 + lr;
            if (r >= n) r = n - 1;
            a[mt] = cvt8(x + (size_t)r * 64 + ks * 32 + lk * 8);
        }
#pragma unroll
        for (int nt = 0; nt < 8; ++nt) {
            bf16x8 b = *(const bf16x8*)(Wf1 + (size_t)((w * 8 + nt) * 1024 + ks * 512 + l * 8));
            acc[0][nt] = MFMA16(a[0], b, acc[0][nt], 0, 0, 0);
            acc[1][nt] = MFMA16(a[1], b, acc[1][nt], 0, 0, 0);
        }
    }
    const float* bptr = (w == 0) ? bq : (w == 1) ? bk : (w == 2) ? bv : bs;
    unsigned char* my = smem + w * 8704;
    if (w == 1) { // k -> fp8 rows of 128B
        unsigned char* lb = my; // [32][144]
#pragma unroll
        for (int nt = 0; nt < 8; ++nt) {
            float bias = bptr[nt * 16 + lr];
#pragma unroll
            for (int mt = 0; mt < 2; ++mt)
#pragma unroll
                for (int i = 0; i < 4; ++i)
                    lb[(mt * 16 + lk * 4 + i) * 144 + nt * 16 + lr] = f2fp8(acc[mt][nt][i] + bias);
        }
#pragma unroll
        for (int p = 0; p < 8; ++p) {
            int rl = p * 4 + lk;
            int r = rb + rl;
            if (r < n) {
                uint2 val = *(const uint2*)(lb + rl * 144 + lr * 8);
                *(uint2*)(k8 + (size_t)r * 128 + lr * 8) = val;
            }
        }
    } else {
        unsigned short* ls = (unsigned short*)my; // [32][136]
#pragma unroll
        for (int nt = 0; nt < 8; ++nt) {
            float bias = bptr[nt * 16 + lr];
#pragma unroll
            for (int mt = 0; mt < 2; ++mt)
#pragma unroll
                for (int i = 0; i < 4; ++i)
                    ls[(mt * 16 + lk * 4 + i) * 136 + nt * 16 + lr] = f2bf(acc[mt][nt][i] + bias);
        }
        unsigned short* outp = (w == 0) ? qs1 : (w == 3) ? qs1 + 128 : v1;
        size_t stride = (w == 2) ? 128 : 256;
#pragma unroll
        for (int p = 0; p < 8; ++p) {
            int rl = p * 4 + lk;
            int r = rb + rl;
            if (r < n) {
                uint4 val = *(const uint4*)(ls + rl * 136 + lr * 8);
                *(uint4*)(outp + (size_t)r * stride + lr * 8) = val;
            }
        }
    }
}

// ---------------- fused scan: block-local exclusive scan + last-block global offsets ----------------

__global__ __launch_bounds__(256) void k_scan(const int* __restrict__ cnt,
                                              int* __restrict__ row,
                                              int* __restrict__ bsum,
                                              int* __restrict__ boff,
                                              int* __restrict__ ctr, int n) {
    __shared__ int wsum[4];
    __shared__ int lastBlk;
    int t = threadIdx.x;
    int base = blockIdx.x * 1024 + t * 4;
    int v0 = (base + 0 < n) ? cnt[base + 0] : 0;
    int v1 = (base + 1 < n) ? cnt[base + 1] : 0;
    int v2 = (base + 2 < n) ? cnt[base + 2] : 0;
    int v3 = (base + 3 < n) ? cnt[base + 3] : 0;
    int s = v0 + v1 + v2 + v3;
    int lane = t & 63, wid = t >> 6;
    int sc = s;
#pragma unroll
    for (int d = 1; d < 64; d <<= 1) {
        int o = __shfl_up(sc, d);
        if (lane >= d) sc += o;
    }
    if (lane == 63) wsum[wid] = sc;
    __syncthreads();
    int woff = 0;
    for (int w = 0; w < wid; ++w) woff += wsum[w];
    int excl = woff + sc - s;
    if (base + 0 < n) row[base + 0] = excl;
    if (base + 1 < n) row[base + 1] = excl + v0;
    if (base + 2 < n) row[base + 2] = excl + v0 + v1;
    if (base + 3 < n) row[base + 3] = excl + v0 + v1 + v2;
    if (t == 255) {
        bsum[blockIdx.x] = woff + sc;
        __threadfence();
        lastBlk = (atomicAdd(ctr, 1) == (int)gridDim.x - 1);
    }
    __syncthreads();
    if (lastBlk && t < 64) {
        __threadfence();
        int v = (t < NBS) ? ((volatile int*)bsum)[t] : 0;
        int sc2 = v;
#pragma unroll
        for (int d = 1; d < 64; d <<= 1) {
            int o = __shfl_up(sc2, d);
            if (t >= d) sc2 += o;
        }
        boff[t] = sc2 - v; // exclusive block offset
        if (t == (N_NODES >> 10)) row[N_NODES] = N_EDGES - (sc2 - v);
    }
}

// ---------------- scatter ----------------

__global__ void k_scat(const int* __restrict__ src, const int* __restrict__ dst,
                       const int* __restrict__ row, const int* __restrict__ boff,
                       const int* __restrict__ rank, int* __restrict__ col) {
    int e = blockIdx.x * 256 + threadIdx.x;
    int de = dst[e];
    col[row[de] + boff[de >> 10] + rank[e]] = src[e];
}

// ---------------- GEMM 2 (MFMA): h1b[N,128]bf16 @ {Wq,Wk,Wv,Ws}[128,32] + b ----------------
// LDS-staged epilogue; outputs (bf16): qs2[N][64] (q 0:32, s 32:64); kv2[N][64] (k 0:32, v 32:64)

__global__ __launch_bounds__(256) void k_gemm2m(
    const unsigned short* __restrict__ h1b, const unsigned short* __restrict__ Wf2,
    const float* __restrict__ bq, const float* __restrict__ bk,
    const float* __restrict__ bv, const float* __restrict__ bs,
    unsigned short* __restrict__ qs2, unsigned short* __restrict__ kv2, int n)
{
    __shared__ unsigned short lds[4][32][72]; // 18.4 KB
    int w = threadIdx.x >> 6;
    int l = threadIdx.x & 63;
    int half = w & 1;
    int rb = blockIdx.x * 64 + (w >> 1) * 32;
    int lr = l & 15, lk = l >> 4;
    f32x4 acc[2][4];
#pragma unroll
    for (int mt = 0; mt < 2; ++mt)
#pragma unroll
        for (int nt = 0; nt < 4; ++nt) acc[mt][nt] = (f32x4){0.f, 0.f, 0.f, 0.f};
#pragma unroll
    for (int ks = 0; ks < 4; ++ks) {
        bf16x8 a[2];
#pragma unroll
        for (int mt = 0; mt < 2; ++mt) {
            int r = rb + mt * 16 + lr;
            if (r >= n) r = n - 1;
            a[mt] = *(const bf16x8*)(h1b + (size_t)r * 128 + ks * 32 + lk * 8);
        }
#pragma unroll
        for (int nt = 0; nt < 4; ++nt) {
            int g = half * 4 + nt;
            bf16x8 b = *(const bf16x8*)(Wf2 + (size_t)((g * 4 + ks) * 512 + l * 8));
            acc[0][nt] = MFMA16(a[0], b, acc[0][nt], 0, 0, 0);
            acc[1][nt] = MFMA16(a[1], b, acc[1][nt], 0, 0, 0);
        }
    }
    // stage: col index lc = nt*16+lr in [0,64); lc<32 -> matA, lc>=32 -> matB
#pragma unroll
    for (int nt = 0; nt < 4; ++nt) {
        int g = half * 4 + nt;
        int mat = g >> 1;
        int c = (g * 16 + lr) & 31;
        const float* bp = (mat == 0) ? bq : (mat == 1) ? bk : (mat == 2) ? bv : bs;
        float bias = bp[c];
#pragma unroll
        for (int mt = 0; mt < 2; ++mt)
#pragma unroll
            for (int i = 0; i < 4; ++i)
                lds[w][mt * 16 + lk * 4 + i][nt * 16 + lr] = f2bf(acc[mt][nt][i] + bias);
    }
    unsigned short* outA = (half == 0) ? qs2 : kv2 + 32; // q : v
    unsigned short* outB = (half == 0) ? kv2 : qs2 + 32; // k : s
    int rl8 = l >> 3, ci = (l & 7) * 4;
#pragma unroll
    for (int p = 0; p < 4; ++p) {
        int rl = p * 8 + rl8;
        int r = rb + rl;
        if (r < n) {
            uint2 va = *(const uint2*)&lds[w][rl][ci];
            *(uint2*)(outA + (size_t)r * 64 + ci) = va;
            uint2 vb = *(const uint2*)&lds[w][rl][32 + ci];
            *(uint2*)(outB + (size_t)r * 64 + ci) = vb;
        }
    }
}

// ---------------- Layer-1 attention aggregate ----------------
// one wave per dst node; lane = slot(0-3)*16 + w(0-15); lane owns channels [w*8, w*8+8).
// 8 edges per iteration. k gathered as fp8 (8B/lane), v as bf16 (16B/lane).

__global__ __launch_bounds__(256) void k_agg1(
    const unsigned short* __restrict__ qs1, const unsigned char* __restrict__ k8,
    const unsigned short* __restrict__ v1,
    const int* __restrict__ row, const int* __restrict__ boff,
    const int* __restrict__ col, uint4* __restrict__ h1b, int n)
{
    int i = blockIdx.x * 4 + (threadIdx.x >> 6);
    if (i >= n) return;
    int lane = threadIdx.x & 63;
    int slot = lane >> 4, w = lane & 15;
    float q[8];
    unpack8(q, *(const uint4*)(qs1 + (size_t)i * 256 + w * 8));
    float acc[8] = {};
    float d = 0.f;
    int s = row[i] + boff[i >> 10];
    int e = row[i + 1] + boff[(i + 1) >> 10];
    for (int t = s; t < e; t += 8) {
        int ta = t + slot, tb = t + 4 + slot;
        bool va = ta < e, vb = tb < e;
        int ja = col[va ? ta : s];
        int jb = col[vb ? tb : s];
        uint2 ka = *(const uint2*)(k8 + (size_t)ja * 128 + w * 8);
        uint2 kb = *(const uint2*)(k8 + (size_t)jb * 128 + w * 8);
        uint4 vA = *(const uint4*)(v1 + (size_t)ja * 128 + w * 8);
        uint4 vB = *(const uint4*)(v1 + (size_t)jb * 128 + w * 8);
        float la = dot8f8(q, ka);
        float lb = dot8f8(q, kb);
        la += __shfl_xor(la, 1);  lb += __shfl_xor(lb, 1);
        la += __shfl_xor(la, 2);  lb += __shfl_xor(lb, 2);
        float wa = va ? __expf(la * SCALE) : 0.f;
        float wb = vb ? __expf(lb * SCALE) : 0.f;
        d += wa + wb;
        acc8(acc, wa, vA);
        acc8(acc, wb, vB);
    }
#pragma unroll
    for (int m = 16; m <= 32; m <<= 1) {
        d += __shfl_xor(d, m);
#pragma unroll
        for (int c = 0; c < 8; ++c) acc[c] += __shfl_xor(acc[c], m);
    }
    if (slot == 0) {
        float inv = (d > 0.f) ? 1.f / d : 0.f;
        float sv[8];
        unpack8(sv, *(const uint4*)(qs1 + (size_t)i * 256 + 128 + w * 8));
        unsigned o[4];
#pragma unroll
        for (int p = 0; p < 4; ++p) {
            float rx = acc[2 * p] * inv + sv[2 * p];
            float ry = acc[2 * p + 1] * inv + sv[2 * p + 1];
            rx = (rx > 0.f) ? rx : expm1f(rx); // ELU
            ry = (ry > 0.f) ? ry : expm1f(ry);
            o[p] = ((unsigned)f2bf(ry) << 16) | (unsigned)f2bf(rx);
        }
        h1b[(size_t)i * 16 + w] = make_uint4(o[0], o[1], o[2], o[3]);
    }
}

// ---------------- Layer-2 attention aggregate ----------------
// one wave per dst node; lane = slot(0-15)*4 + qr(0-3); 16 edges/iteration.

__global__ __launch_bounds__(256) void k_agg2(
    const unsigned short* __restrict__ qs2, const unsigned short* __restrict__ kv2,
    const int* __restrict__ row, const int* __restrict__ boff,
    const int* __restrict__ col, float* __restrict__ out, int n)
{
    int i = blockIdx.x * 4 + (threadIdx.x >> 6);
    if (i >= n) return;
    int lane = threadIdx.x & 63;
    int slot = lane >> 2, qr = lane & 3;
    float q[8];
    unpack8(q, *(const uint4*)(qs2 + (size_t)i * 64 + qr * 8));
    float acc[8] = {};
    float d = 0.f;
    int s = row[i] + boff[i >> 10];
    int e = row[i + 1] + boff[(i + 1) >> 10];
    for (int t = s; t < e; t += 16) {
        int te = t + slot;
        bool va = te < e;
        int j = col[va ? te : s];
        const unsigned short* p = kv2 + (size_t)j * 64;
        uint4 ku = *(const uint4*)(p + qr * 8);
        uint4 vu = *(const uint4*)(p + 32 + qr * 8);
        float lg = dot8(q, ku);
        lg += __shfl_xor(lg, 1);
        lg += __shfl_xor(lg, 2);
        float wv = va ? __expf(lg * SCALE) : 0.f;
        d += wv;
        acc8(acc, wv, vu);
    }
#pragma unroll
    for (int m = 4; m <= 32; m <<= 1) {
        d += __shfl_xor(d, m);
#pragma unroll
        for (int c = 0; c < 8; ++c) acc[c] += __shfl_xor(acc[c], m);
    }
    if (slot == 0) {
        float inv = (d > 0.f) ? 1.f / d : 0.f;
        float sv[8];
        unpack8(sv, *(const uint4*)(qs2 + (size_t)i * 64 + 32 + qr * 8));
        float4 o0, o1;
        o0.x = acc[0] * inv + sv[0];
        o0.y = acc[1] * inv + sv[1];
        o0.z = acc[2] * inv + sv[2];
        o0.w = acc[3] * inv + sv[3];
        o1.x = acc[4] * inv + sv[4];
        o1.y = acc[5] * inv + sv[5];
        o1.z = acc[6] * inv + sv[6];
        o1.w = acc[7] * inv + sv[7];
        *(float4*)&out[(size_t)i * 32 + qr * 8] = o0;
        *(float4*)&out[(size_t)i * 32 + qr * 8 + 4] = o1;
    }
}

// ---------------- launch ----------------

extern "C" void kernel_launch(void* const* d_in, const int* in_sizes, int n_in,
                              void* d_out, int out_size, void* d_ws, size_t ws_size,
                              hipStream_t stream)
{
    const int N = N_NODES, E = N_EDGES;
    const float* x   = (const float*)d_in[0];
    const int* edge  = (const int*)d_in[1];
    const int* src   = edge;       // edge_index[0]
    const int* dst   = edge + E;   // edge_index[1]
    const float* Wq1 = (const float*)d_in[2];  const float* bq1 = (const float*)d_in[3];
    const float* Wk1 = (const float*)d_in[4];  const float* bk1 = (const float*)d_in[5];
    const float* Wv1 = (const float*)d_in[6];  const float* bv1 = (const float*)d_in[7];
    const float* Ws1 = (const float*)d_in[8];  const float* bs1 = (const float*)d_in[9];
    const float* Wq2 = (const float*)d_in[10]; const float* bq2 = (const float*)d_in[11];
    const float* Wk2 = (const float*)d_in[12]; const float* bk2 = (const float*)d_in[13];
    const float* Wv2 = (const float*)d_in[14]; const float* bv2 = (const float*)d_in[15];
    const float* Ws2 = (const float*)d_in[16]; const float* bs2 = (const float*)d_in[17];

    char* ws = (char*)d_ws;
    size_t off = 0;
    auto alloc = [&](size_t bytes) -> void* {
        void* p = ws + off;
        off += (bytes + 255) & ~(size_t)255;
        return p;
    };
    unsigned short* qs1 = (unsigned short*)alloc((size_t)N * 256 * 2); // 25.6 MB
    unsigned char*  k8  = (unsigned char*)alloc((size_t)N * 128);      //  6.4 MB
    unsigned short* v1  = (unsigned short*)alloc((size_t)N * 128 * 2); // 12.8 MB
    unsigned short* h1b = (unsigned short*)alloc((size_t)N * 128 * 2); // 12.8 MB
    unsigned short* qs2 = (unsigned short*)alloc((size_t)N * 64 * 2);  //  6.4 MB
    unsigned short* kv2 = (unsigned short*)alloc((size_t)N * 64 * 2);  //  6.4 MB
    unsigned short* Wf1 = (unsigned short*)alloc(32768 * 2);
    unsigned short* Wf2 = (unsigned short*)alloc(16384 * 2);
    int* row_ptr  = (int*)alloc((size_t)(N + 1) * 4);
    int* cnt      = (int*)alloc((size_t)(N + 64) * 4); // cnt[N] + ctr
    int* ctr      = cnt + N;
    int* rank     = (int*)alloc((size_t)E * 4);
    int* colb     = (int*)alloc((size_t)E * 4);
    int* bsum     = (int*)alloc(64 * 4);
    int* boff     = (int*)alloc(64 * 4);

    hipMemsetAsync(cnt, 0, (size_t)(N + 64) * 4, stream);
    k_prep<<<192, 256, 0, stream>>>(Wq1, Wk1, Wv1, Ws1, Wq2, Wk2, Wv2, Ws2, Wf1, Wf2);
    k_big<<<GB1 + HB, 256, 0, stream>>>(dst, cnt, rank,
                                        x, Wf1, bq1, bk1, bv1, bs1, qs1, k8, v1, N);
    k_scan<<<NBS, 256, 0, stream>>>(cnt, row_ptr, bsum, boff, ctr, N);
    k_scat<<<HB, 256, 0, stream>>>(src, dst, row_ptr, boff, rank, colb);
    k_agg1<<<(N + 3) / 4, 256, 0, stream>>>(qs1, k8, v1, row_ptr, boff, colb, (uint4*)h1b, N);
    k_gemm2m<<<(N + 63) / 64, 256, 0, stream>>>(h1b, Wf2, bq2, bk2, bv2, bs2, qs2, kv2, N);
    k_agg2<<<(N + 3) / 4, 256, 0, stream>>>(qs2, kv2, row_ptr, boff, colb, (float*)d_out, N);
}